// Round 5
// baseline (920.350 us; speedup 1.0000x reference)
//
#include <hip/hip_runtime.h>

#define DEPTH   4
#define BSZ     2
#define LSEQ    1024
#define DMODEL  1024
#define NHEAD   16
#define HDIM    64
#define MROWS   (BSZ*LSEQ)    // 2048
#define INNER   2730
#define INNERP  2752
#define N1      (2*INNER)     // 5460
#define N1P     (2*INNERP)    // 5504
#define LOG2E   1.4426950408889634f
#define NSPLIT  4

typedef __bf16 bf16;
typedef bf16  bf16x8 __attribute__((ext_vector_type(8)));
typedef float f32x4  __attribute__((ext_vector_type(4)));
typedef uint32_t u32x4 __attribute__((ext_vector_type(4)));

__device__ inline f32x4 mfma16(bf16x8 a, bf16x8 b, f32x4 c) {
  return __builtin_amdgcn_mfma_f32_16x16x32_bf16(a, b, c, 0, 0, 0);
}

__device__ inline void gload_lds16(const void* g, void* l) {
  __builtin_amdgcn_global_load_lds(
      (const __attribute__((address_space(1))) void*)g,
      (__attribute__((address_space(3))) void*)l, 16, 0, 0);
}

// ---------------- weight conversion ----------------
__global__ void conv_bf16_kernel(const float* __restrict__ src, bf16* __restrict__ dst, size_t n) {
  size_t i = ((size_t)blockIdx.x * 256 + threadIdx.x) * 8;
  if (i >= n) return;
  float4 v0 = *(const float4*)(src + i);
  float4 v1 = *(const float4*)(src + i + 4);
  bf16x8 o = { (bf16)v0.x,(bf16)v0.y,(bf16)v0.z,(bf16)v0.w,
               (bf16)v1.x,(bf16)v1.y,(bf16)v1.z,(bf16)v1.w };
  *(bf16x8*)(dst + i) = o;
}

__global__ void conv_w1_kernel(const float* __restrict__ src, bf16* __restrict__ dst) {
  size_t i = ((size_t)blockIdx.x * 256 + threadIdx.x) * 8;
  const size_t tot = (size_t)DEPTH * N1P * DMODEL;
  if (i >= tot) return;
  int d  = (int)(i / ((size_t)N1P * DMODEL));
  int rem = (int)(i % ((size_t)N1P * DMODEL));
  int rp = rem / DMODEL, k = rem % DMODEL;
  int p2 = rp >> 4, w = rp & 15;
  int col = ((p2 >> 1) << 4) + w;
  bf16x8 o;
  if (col >= INNER) {
    o = (bf16x8)(bf16)0.f;
  } else {
    int rs = (p2 & 1) ? (INNER + col) : col;
    const float* s = src + ((size_t)d * N1 + rs) * DMODEL + k;
    float4 v0 = *(const float4*)s;
    float4 v1 = *(const float4*)(s + 4);
    o = bf16x8{ (bf16)v0.x,(bf16)v0.y,(bf16)v0.z,(bf16)v0.w,
                (bf16)v1.x,(bf16)v1.y,(bf16)v1.z,(bf16)v1.w };
  }
  *(bf16x8*)(dst + i) = o;
}

__global__ void conv_b1_kernel(const float* __restrict__ src, float* __restrict__ dst) {
  int i = blockIdx.x * 256 + threadIdx.x;
  if (i >= DEPTH * N1P) return;
  int d = i / N1P, rp = i % N1P;
  int p2 = rp >> 4, w = rp & 15;
  int col = ((p2 >> 1) << 4) + w;
  float v = 0.f;
  if (col < INNER) v = src[d * N1 + ((p2 & 1) ? (INNER + col) : col)];
  dst[i] = v;
}

__global__ void conv_w2_kernel(const float* __restrict__ src, bf16* __restrict__ dst) {
  size_t i = ((size_t)blockIdx.x * 256 + threadIdx.x) * 8;
  const size_t tot = (size_t)DEPTH * DMODEL * INNERP;
  if (i >= tot) return;
  size_t dn = i / INNERP;
  int kp = (int)(i % INNERP);
  const float* s = src + dn * INNER;
  bf16x8 o;
  #pragma unroll
  for (int j = 0; j < 8; ++j) {
    int k = kp + j;
    o[j] = (k < INNER) ? (bf16)s[k] : (bf16)0.f;
  }
  *(bf16x8*)(dst + i) = o;
}

// ---------------- RMSNorm ----------------
template<bool OUT_BF16>
__global__ __launch_bounds__(256) void rmsnorm_kernel(const float* __restrict__ x,
    const float* __restrict__ gamma, void* __restrict__ out) {
  const int row = blockIdx.x;
  const int tid = threadIdx.x;
  const float4 v = *(const float4*)(x + (size_t)row * DMODEL + tid * 4);
  float ss = v.x*v.x + v.y*v.y + v.z*v.z + v.w*v.w;
  for (int m = 1; m < 64; m <<= 1) ss += __shfl_xor(ss, m);
  __shared__ float ws4[4];
  if ((tid & 63) == 0) ws4[tid >> 6] = ss;
  __syncthreads();
  float tot = ws4[0] + ws4[1] + ws4[2] + ws4[3];
  float scale = 32.0f / fmaxf(sqrtf(tot), 1e-12f);
  const float4 g = *(const float4*)(gamma + tid * 4);
  float o0 = v.x*scale*g.x, o1 = v.y*scale*g.y, o2 = v.z*scale*g.z, o3 = v.w*scale*g.w;
  size_t p = (size_t)row * DMODEL + tid * 4;
  if (OUT_BF16) {
    bf16* ob = (bf16*)out;
    ob[p+0] = (bf16)o0; ob[p+1] = (bf16)o1; ob[p+2] = (bf16)o2; ob[p+3] = (bf16)o3;
  } else {
    *(float4*)((float*)out + p) = make_float4(o0, o1, o2, o3);
  }
}

// ---------------- GEMM: C(2048xNN) = A(2048xKK) @ W(NNxKK)^T + bias [+res] ----
// All dims compile-time; per-thread pointers advance by 64 elems/K-step;
// LDS chunk XOR swizzle (phys chunk = logical ^ (row&7)) applied on the
// global source (for global_load_lds) and on the ds_read offset.
// EPI: 0 = bf16 out, 1 = f32 out + residual add, 2 = fused GEGLU.
template<int TN, int EPI, int NN, int KK>
__global__ __launch_bounds__(256) void gemm_bt(const bf16* __restrict__ A,
    const bf16* __restrict__ Bw, const float* __restrict__ bias,
    const float* __restrict__ res, void* __restrict__ Cout) {
  constexpr int NFR = TN / 32;
  constexpr int BCH = TN / 32;
  constexpr int nk = KK >> 6;
  __shared__ __attribute__((aligned(16))) bf16 As[2 * 128 * 64];
  __shared__ __attribute__((aligned(16))) bf16 Bs[2 * TN * 64];
  const int tid  = threadIdx.x;
  const int lane = tid & 63;
  const int wid  = tid >> 6;
  const int wr = wid >> 1, wc = wid & 1;
  const int m0 = blockIdx.y * 128;
  const int n0 = blockIdx.x * TN;
  const int q = lane & 15, G = lane >> 4;
  const int s7 = q & 7;
  const int srow = tid >> 3;
  const int scol = ((tid & 7) ^ (srow & 7)) << 3;

  const bf16* aSrc = A  + (size_t)(m0 + srow) * KK + scol;
  const bf16* bSrc = Bw + (size_t)(n0 + srow) * KK + scol;
  const int rdA = (wr * 64 + q) * 64;          // + m*1024 + kc
  const int rdB = (wc * (TN/2) + q) * 64;      // + n*1024 + kc
  const int kc0 = ((0 * 4 + G) ^ s7) << 3;
  const int kc1 = ((1 * 4 + G) ^ s7) << 3;
  const int stO = wid * 512;                   // LDS store base (+ j*2048)

  f32x4 acc[4][NFR] = {};

  auto stage = [&](int nxt) {
    bf16* aDst = As + nxt * (128 * 64) + stO;
    bf16* bDst = Bs + nxt * (TN * 64) + stO;
    #pragma unroll
    for (int j = 0; j < 4; ++j)
      gload_lds16(aSrc + (size_t)j * 32 * KK, aDst + j * 2048);
    #pragma unroll
    for (int j = 0; j < BCH; ++j)
      gload_lds16(bSrc + (size_t)j * 32 * KK, bDst + j * 2048);
    aSrc += 64; bSrc += 64;
  };

  stage(0);
  asm volatile("s_waitcnt vmcnt(0)" ::: "memory");
  __syncthreads();

  int cur = 0;
  for (int kt = 0; kt < nk; ++kt) {
    if (kt + 1 < nk) stage(cur ^ 1);
    const bf16* rA = As + cur * (128 * 64) + rdA;
    const bf16* rB = Bs + cur * (TN * 64) + rdB;
    #pragma unroll
    for (int kk = 0; kk < 2; ++kk) {
      const int kc = kk ? kc1 : kc0;
      bf16x8 af[4], bfr[NFR];
      #pragma unroll
      for (int m = 0; m < 4; ++m)
        af[m] = *(const bf16x8*)(rA + m * 1024 + kc);
      #pragma unroll
      for (int n = 0; n < NFR; ++n)
        bfr[n] = *(const bf16x8*)(rB + n * 1024 + kc);
      #pragma unroll
      for (int m = 0; m < 4; ++m)
        #pragma unroll
        for (int n = 0; n < NFR; ++n)
          acc[m][n] = mfma16(af[m], bfr[n], acc[m][n]);
    }
    asm volatile("s_waitcnt vmcnt(0)" ::: "memory");
    __syncthreads();
    cur ^= 1;
  }

  const int rb = G << 2;
  const int cl = q;
  if (EPI == 2) {
    #pragma unroll
    for (int m = 0; m < 4; ++m) {
      #pragma unroll
      for (int np = 0; np < NFR/2; ++np) {
        int ca = n0 + wc*(TN/2) + (2*np)*16 + cl;
        int cg = ca + 16;
        float ba = bias[ca], bg = bias[cg];
        int colo = ((ca >> 5) << 4) + cl;
        #pragma unroll
        for (int r = 0; r < 4; ++r) {
          int row = m0 + wr*64 + m*16 + rb + r;
          float av = acc[m][2*np][r] + ba;
          float gv = acc[m][2*np+1][r] + bg;
          float gl = 0.5f * gv * (1.f + erff(gv * 0.70710678118654752f));
          ((bf16*)Cout)[(size_t)row * (NN >> 1) + colo] = (bf16)(av * gl);
        }
      }
    }
  } else {
    #pragma unroll
    for (int m = 0; m < 4; ++m) {
      #pragma unroll
      for (int n = 0; n < NFR; ++n) {
        int col = n0 + wc*(TN/2) + n*16 + cl;
        float bv = bias[col];
        #pragma unroll
        for (int r = 0; r < 4; ++r) {
          int row = m0 + wr*64 + m*16 + rb + r;
          float v = acc[m][n][r] + bv;
          size_t p = (size_t)row * NN + col;
          if (EPI == 1) ((float*)Cout)[p] = v + res[p];
          else          ((bf16*)Cout)[p] = (bf16)v;
        }
      }
    }
  }
}

// ---------------- Flash attention, split-KV=4, ALiBi, KVBLK=64 ----------------
__global__ __launch_bounds__(256) void attn_kernel(const bf16* __restrict__ qkv,
    const float* __restrict__ slopes, float* __restrict__ Opart, float* __restrict__ ml) {
  const int tid = threadIdx.x, lane = tid & 63, wid = tid >> 6;
  const int bh = blockIdx.y;
  const int b = bh >> 4, h = bh & 15;
  const int kvz = blockIdx.z;
  const int kv0 = kvz * (LSEQ / NSPLIT);
  const float slope2 = slopes[h] * LOG2E;
  const float SC = 0.125f * LOG2E;
  const int qw = blockIdx.x * 64 + wid * 16;

  __shared__ __attribute__((aligned(16))) bf16     Kt[64 * 72];
  __shared__ __attribute__((aligned(16))) uint32_t V32[64 * 36];
  __shared__ __attribute__((aligned(16))) uint32_t Pl32[4][16 * 36];

  const size_t rs = 3 * DMODEL;
  const size_t base = (size_t)b * LSEQ * rs;

  bf16x8 qf[2];
  {
    const bf16* p = qkv + base + (size_t)(qw + (lane & 15)) * rs + h * HDIM + ((lane >> 4) << 3);
    qf[0] = *(const bf16x8*)p;
    qf[1] = *(const bf16x8*)(p + 32);
  }

  f32x4 accO[4] = {};
  float mrow[4], lrow[4];
  #pragma unroll
  for (int r = 0; r < 4; ++r) { mrow[r] = -1e30f; lrow[r] = 0.f; }

  const int trow = tid >> 2;
  const int tcol = (tid & 3) << 4;

  bf16x8 kreg0, kreg1, vreg0, vreg1;
  {
    const bf16* kp = qkv + base + (size_t)(kv0 + trow) * rs + DMODEL + h * HDIM + tcol;
    kreg0 = *(const bf16x8*)kp; kreg1 = *(const bf16x8*)(kp + 8);
    const bf16* vp = qkv + base + (size_t)(kv0 + trow) * rs + 2 * DMODEL + h * HDIM + tcol;
    vreg0 = *(const bf16x8*)vp; vreg1 = *(const bf16x8*)(vp + 8);
  }

  uint32_t* P32w = &Pl32[wid][0];
  const int q = lane & 15, G = lane >> 4;

  for (int kv = kv0; kv < kv0 + LSEQ / NSPLIT; kv += 64) {
    __syncthreads();
    *(bf16x8*)(Kt + trow * 72 + tcol)     = kreg0;
    *(bf16x8*)(Kt + trow * 72 + tcol + 8) = kreg1;
    {
      u32x4 va = __builtin_bit_cast(u32x4, vreg0);
      u32x4 vb = __builtin_bit_cast(u32x4, vreg1);
      u32x4 pa, pb;
      #pragma unroll
      for (int i = 0; i < 4; ++i) {
        pa[i] = (uint32_t)__shfl_xor((int)va[i], 4);
        pb[i] = (uint32_t)__shfl_xor((int)vb[i], 4);
      }
      const bool oddk = (trow & 1);
      const int d0 = tcol + (oddk ? 8 : 0);
      u32x4 m = oddk ? vb : va;
      u32x4 oo = oddk ? pb : pa;
      const int kpair = trow >> 1;
      const int swz = kpair ^ ((d0 >> 3) << 1);
      #pragma unroll
      for (int i = 0; i < 4; ++i) {
        uint32_t lo = oddk ? oo[i] : m[i];
        uint32_t hi = oddk ? m[i] : oo[i];
        uint32_t w0 = (lo & 0xffffu) | (hi << 16);
        uint32_t w1 = (lo >> 16) | (hi & 0xffff0000u);
        V32[(d0 + 2*i)     * 36 + swz] = w0;
        V32[(d0 + 2*i + 1) * 36 + swz] = w1;
      }
    }
    __syncthreads();

    if (kv + 64 < kv0 + LSEQ / NSPLIT) {
      const bf16* kp = qkv + base + (size_t)(kv + 64 + trow) * rs + DMODEL + h * HDIM + tcol;
      kreg0 = *(const bf16x8*)kp; kreg1 = *(const bf16x8*)(kp + 8);
      const bf16* vp = qkv + base + (size_t)(kv + 64 + trow) * rs + 2 * DMODEL + h * HDIM + tcol;
      vreg0 = *(const bf16x8*)vp; vreg1 = *(const bf16x8*)(vp + 8);
    }

    f32x4 sacc[4] = {};
    __builtin_amdgcn_s_setprio(1);
    #pragma unroll
    for (int nt = 0; nt < 4; ++nt) {
      const bf16* kb = Kt + (nt * 16 + q) * 72 + (G << 3);
      sacc[nt] = mfma16(qf[0], *(const bf16x8*)kb, sacc[nt]);
      sacc[nt] = mfma16(qf[1], *(const bf16x8*)(kb + 32), sacc[nt]);
    }
    __builtin_amdgcn_s_setprio(0);

    float pv[4][4];
    #pragma unroll
    for (int r = 0; r < 4; ++r) {
      int qi = qw + (G << 2) + r;
      float vmax = -1e30f;
      #pragma unroll
      for (int nt = 0; nt < 4; ++nt) {
        int kj = kv + nt * 16 + q;
        float s = sacc[nt][r] * SC - slope2 * fabsf((float)(qi - kj));
        pv[nt][r] = s;
        vmax = fmaxf(vmax, s);
      }
      for (int m = 1; m < 16; m <<= 1) vmax = fmaxf(vmax, __shfl_xor(vmax, m));
      float newmax = fmaxf(mrow[r], vmax);
      float ef = exp2f(mrow[r] - newmax);
      float rsum = 0.f;
      #pragma unroll
      for (int nt = 0; nt < 4; ++nt) {
        float p = exp2f(pv[nt][r] - newmax);
        pv[nt][r] = p;
        rsum += p;
      }
      for (int m = 1; m < 16; m <<= 1) rsum += __shfl_xor(rsum, m);
      lrow[r] = lrow[r] * ef + rsum;
      mrow[r] = newmax;
      #pragma unroll
      for (int dn = 0; dn < 4; ++dn) accO[dn][r] *= ef;
    }

    #pragma unroll
    for (int nt = 0; nt < 4; ++nt) {
      #pragma unroll
      for (int r = 0; r < 4; ++r) {
        float other = __shfl_xor(pv[nt][r], 1);
        if (!(lane & 1)) {
          uint32_t w;
          asm("v_cvt_pk_bf16_f32 %0, %1, %2" : "=v"(w) : "v"(pv[nt][r]), "v"(other));
          int prow = (G << 2) + r;
          int col2 = nt * 8 + (q >> 1);
          P32w[prow * 36 + (col2 ^ ((prow & 7) << 1))] = w;
        }
      }
    }
    asm volatile("s_waitcnt lgkmcnt(0)" ::: "memory");

    __builtin_amdgcn_s_setprio(1);
    #pragma unroll
    for (int chunk = 0; chunk < 2; ++chunk) {
      u32x4 praw = *(const u32x4*)(P32w + q * 36 + chunk * 16 + 4 * (G ^ ((q >> 1) & 3)));
      if (q & 1) praw = __builtin_shufflevector(praw, praw, 2, 3, 0, 1);
      bf16x8 pf = __builtin_bit_cast(bf16x8, praw);
      #pragma unroll
      for (int dn = 0; dn < 4; ++dn) {
        const int d = dn * 16 + q;
        u32x4 raw = *(const u32x4*)(V32 + d * 36 + chunk * 16 + 4 * (G ^ dn));
        if ((lane >> 3) & 1) raw = __builtin_shufflevector(raw, raw, 2, 3, 0, 1);
        bf16x8 vf = __builtin_bit_cast(bf16x8, raw);
        accO[dn] = mfma16(pf, vf, accO[dn]);
      }
    }
    __builtin_amdgcn_s_setprio(0);
  }

  #pragma unroll
  for (int r = 0; r < 4; ++r) {
    int qr = qw + (G << 2) + r;
    size_t obase = ((size_t)(kvz * 32 + bh) * LSEQ + qr) * HDIM;
    #pragma unroll
    for (int dn = 0; dn < 4; ++dn)
      Opart[obase + dn * 16 + q] = accO[dn][r];
    if (q == 0) {
      size_t mb = ((size_t)(kvz * 32 + bh) * LSEQ + qr) * 2;
      ml[mb]     = mrow[r];
      ml[mb + 1] = lrow[r];
    }
  }
}

// combine NSPLIT kv-parts
__global__ __launch_bounds__(256) void attn_combine(const float* __restrict__ Opart,
    const float* __restrict__ ml, bf16* __restrict__ o) {
  int idx = blockIdx.x * 256 + threadIdx.x;
  int bh = idx >> 14;
  int rem = idx & 16383;
  int qr = rem >> 4;
  int d4 = (rem & 15) << 2;
  float mz[NSPLIT], lz[NSPLIT];
  float m = -1e30f;
  #pragma unroll
  for (int z = 0; z < NSPLIT; ++z) {
    size_t rz = ((size_t)(z * 32 + bh) * LSEQ + qr) * 2;
    mz[z] = ml[rz]; lz[z] = ml[rz + 1];
    m = fmaxf(m, mz[z]);
  }
  float wz[NSPLIT];
  float l = 0.f;
  #pragma unroll
  for (int z = 0; z < NSPLIT; ++z) { wz[z] = exp2f(mz[z] - m); l += lz[z] * wz[z]; }
  float inv = 1.f / l;
  float ax = 0, ay = 0, az = 0, aw = 0;
  #pragma unroll
  for (int z = 0; z < NSPLIT; ++z) {
    size_t rz = (size_t)(z * 32 + bh) * LSEQ + qr;
    float4 ov = *(const float4*)(Opart + rz * HDIM + d4);
    ax += ov.x * wz[z]; ay += ov.y * wz[z]; az += ov.z * wz[z]; aw += ov.w * wz[z];
  }
  int b = bh >> 4, h = bh & 15;
  bf16* op = o + ((size_t)(b * LSEQ + qr) * DMODEL + h * HDIM + d4);
  op[0] = (bf16)(ax * inv);
  op[1] = (bf16)(ay * inv);
  op[2] = (bf16)(az * inv);
  op[3] = (bf16)(aw * inv);
}

// ---------------- host ----------------
extern "C" void kernel_launch(void* const* d_in, const int* in_sizes, int n_in,
                              void* d_out, int out_size, void* d_ws, size_t ws_size,
                              hipStream_t stream) {
  const float* x_in      = (const float*)d_in[0];
  const float* slopes    = (const float*)d_in[1];
  const float* g_attn    = (const float*)d_in[2];
  const float* w_in      = (const float*)d_in[3];
  const float* b_in      = (const float*)d_in[4];
  const float* w_out     = (const float*)d_in[5];
  const float* b_out     = (const float*)d_in[6];
  const float* g_ff      = (const float*)d_in[7];
  const float* w1        = (const float*)d_in[8];
  const float* b1        = (const float*)d_in[9];
  const float* w2        = (const float*)d_in[10];
  const float* b2        = (const float*)d_in[11];
  const float* g_final   = (const float*)d_in[12];

  char* p = (char*)d_ws;
  float* xw   = (float*)p;              p += (size_t)MROWS * DMODEL * 4;
  bf16* abuf  = (bf16*)p;               p += (size_t)MROWS * DMODEL * 2;
  bf16* qkvb  = (bf16*)p;               p += (size_t)MROWS * 3 * DMODEL * 2;
  bf16* obuf  = (bf16*)p;               p += (size_t)MROWS * DMODEL * 2;
  bf16* gbuf  = (bf16*)p;               p += (size_t)MROWS * INNERP * 2;
  float* Opart = (float*)p;             p += (size_t)NSPLIT * 32 * LSEQ * HDIM * 4;
  float* mlb   = (float*)p;             p += (size_t)NSPLIT * 32 * LSEQ * 2 * 4;
  bf16* w_in_b  = (bf16*)p;             p += (size_t)DEPTH * 3 * DMODEL * DMODEL * 2;
  bf16* w_out_b = (bf16*)p;             p += (size_t)DEPTH * DMODEL * DMODEL * 2;
  bf16* w1p     = (bf16*)p;             p += (size_t)DEPTH * N1P * DMODEL * 2;
  bf16* w2p     = (bf16*)p;             p += (size_t)DEPTH * DMODEL * INNERP * 2;
  float* b1p    = (float*)p;            p += (size_t)DEPTH * N1P * 4;

  hipMemcpyAsync(xw, x_in, (size_t)MROWS * DMODEL * 4, hipMemcpyDeviceToDevice, stream);

  conv_bf16_kernel<<<6144, 256, 0, stream>>>(w_in, w_in_b, (size_t)DEPTH * 3 * DMODEL * DMODEL);
  conv_bf16_kernel<<<2048, 256, 0, stream>>>(w_out, w_out_b, (size_t)DEPTH * DMODEL * DMODEL);
  conv_w1_kernel<<<11008, 256, 0, stream>>>(w1, w1p);
  conv_b1_kernel<<<86, 256, 0, stream>>>(b1, b1p);
  conv_w2_kernel<<<5504, 256, 0, stream>>>(w2, w2p);

  for (int i = 0; i < DEPTH; ++i) {
    rmsnorm_kernel<true><<<MROWS, 256, 0, stream>>>(xw, g_attn + i * DMODEL, abuf);
    gemm_bt<64, 0, 3072, 1024><<<dim3(48, 16), 256, 0, stream>>>(
        abuf, w_in_b + (size_t)i * 3 * DMODEL * DMODEL, b_in + i * 3 * DMODEL,
        nullptr, qkvb);
    attn_kernel<<<dim3(16, 32, NSPLIT), 256, 0, stream>>>(qkvb, slopes, Opart, mlb);
    attn_combine<<<2048, 256, 0, stream>>>(Opart, mlb, obuf);
    gemm_bt<64, 1, 1024, 1024><<<dim3(16, 16), 256, 0, stream>>>(
        obuf, w_out_b + (size_t)i * DMODEL * DMODEL, b_out + i * DMODEL,
        xw, xw);
    rmsnorm_kernel<true><<<MROWS, 256, 0, stream>>>(xw, g_ff + i * DMODEL, abuf);
    gemm_bt<128, 2, 5504, 1024><<<dim3(43, 16), 256, 0, stream>>>(
        abuf, w1p + (size_t)i * N1P * DMODEL, b1p + i * N1P,
        nullptr, gbuf);
    gemm_bt<64, 1, 1024, 2752><<<dim3(16, 16), 256, 0, stream>>>(
        gbuf, w2p + (size_t)i * DMODEL * INNERP, b2 + i * DMODEL,
        xw, xw);
  }
  rmsnorm_kernel<false><<<MROWS, 256, 0, stream>>>(xw, g_final, d_out);
}

// Round 6
// 846.741 us; speedup vs baseline: 1.0869x; 1.0869x over previous
//
#include <hip/hip_runtime.h>

#define DEPTH   4
#define BSZ     2
#define LSEQ    1024
#define DMODEL  1024
#define NHEAD   16
#define HDIM    64
#define MROWS   (BSZ*LSEQ)    // 2048
#define INNER   2730
#define INNERP  2752
#define N1      (2*INNER)     // 5460
#define N1P     (2*INNERP)    // 5504
#define LOG2E   1.4426950408889634f
#define NSPLIT  2

typedef __bf16 bf16;
typedef bf16  bf16x8 __attribute__((ext_vector_type(8)));
typedef float f32x4  __attribute__((ext_vector_type(4)));
typedef uint32_t u32x4 __attribute__((ext_vector_type(4)));

__device__ inline f32x4 mfma16(bf16x8 a, bf16x8 b, f32x4 c) {
  return __builtin_amdgcn_mfma_f32_16x16x32_bf16(a, b, c, 0, 0, 0);
}

__device__ inline void gload_lds16(const void* g, void* l) {
  __builtin_amdgcn_global_load_lds(
      (const __attribute__((address_space(1))) void*)g,
      (__attribute__((address_space(3))) void*)l, 16, 0, 0);
}

// ---------------- weight conversion (vectorized stores) ----------------
__global__ void conv_bf16_kernel(const float* __restrict__ src, bf16* __restrict__ dst, size_t n) {
  size_t i = ((size_t)blockIdx.x * 256 + threadIdx.x) * 8;
  if (i >= n) return;
  float4 v0 = *(const float4*)(src + i);
  float4 v1 = *(const float4*)(src + i + 4);
  bf16x8 o = { (bf16)v0.x,(bf16)v0.y,(bf16)v0.z,(bf16)v0.w,
               (bf16)v1.x,(bf16)v1.y,(bf16)v1.z,(bf16)v1.w };
  *(bf16x8*)(dst + i) = o;
}

// ff_w1 (DEPTH,5460,1024) -> padded interleaved (DEPTH,5504,1024):
// padded row rp: p=rp>>4, w=rp&15, col=(p>>1)*16+w; even p -> a-row col,
// odd p -> gate-row INNER+col; col>=INNER -> zero.
__global__ void conv_w1_kernel(const float* __restrict__ src, bf16* __restrict__ dst) {
  size_t i = ((size_t)blockIdx.x * 256 + threadIdx.x) * 8;
  const size_t tot = (size_t)DEPTH * N1P * DMODEL;
  if (i >= tot) return;
  int d  = (int)(i / ((size_t)N1P * DMODEL));
  int rem = (int)(i % ((size_t)N1P * DMODEL));
  int rp = rem / DMODEL, k = rem % DMODEL;
  int p2 = rp >> 4, w = rp & 15;
  int col = ((p2 >> 1) << 4) + w;
  bf16x8 o;
  if (col >= INNER) {
    o = (bf16x8)(bf16)0.f;
  } else {
    int rs = (p2 & 1) ? (INNER + col) : col;
    const float* s = src + ((size_t)d * N1 + rs) * DMODEL + k;
    float4 v0 = *(const float4*)s;
    float4 v1 = *(const float4*)(s + 4);
    o = bf16x8{ (bf16)v0.x,(bf16)v0.y,(bf16)v0.z,(bf16)v0.w,
                (bf16)v1.x,(bf16)v1.y,(bf16)v1.z,(bf16)v1.w };
  }
  *(bf16x8*)(dst + i) = o;
}

__global__ void conv_b1_kernel(const float* __restrict__ src, float* __restrict__ dst) {
  int i = blockIdx.x * 256 + threadIdx.x;
  if (i >= DEPTH * N1P) return;
  int d = i / N1P, rp = i % N1P;
  int p2 = rp >> 4, w = rp & 15;
  int col = ((p2 >> 1) << 4) + w;
  float v = 0.f;
  if (col < INNER) v = src[d * N1 + ((p2 & 1) ? (INNER + col) : col)];
  dst[i] = v;
}

__global__ void conv_w2_kernel(const float* __restrict__ src, bf16* __restrict__ dst) {
  size_t i = ((size_t)blockIdx.x * 256 + threadIdx.x) * 8;
  const size_t tot = (size_t)DEPTH * DMODEL * INNERP;
  if (i >= tot) return;
  size_t dn = i / INNERP;
  int kp = (int)(i % INNERP);
  const float* s = src + dn * INNER;
  bf16x8 o;
  #pragma unroll
  for (int j = 0; j < 8; ++j) {
    int k = kp + j;
    o[j] = (k < INNER) ? (bf16)s[k] : (bf16)0.f;
  }
  *(bf16x8*)(dst + i) = o;
}

// ---------------- RMSNorm ----------------
template<bool OUT_BF16>
__global__ __launch_bounds__(256) void rmsnorm_kernel(const float* __restrict__ x,
    const float* __restrict__ gamma, void* __restrict__ out) {
  const int row = blockIdx.x;
  const int tid = threadIdx.x;
  const float4 v = *(const float4*)(x + (size_t)row * DMODEL + tid * 4);
  float ss = v.x*v.x + v.y*v.y + v.z*v.z + v.w*v.w;
  for (int m = 1; m < 64; m <<= 1) ss += __shfl_xor(ss, m);
  __shared__ float ws4[4];
  if ((tid & 63) == 0) ws4[tid >> 6] = ss;
  __syncthreads();
  float tot = ws4[0] + ws4[1] + ws4[2] + ws4[3];
  float scale = 32.0f / fmaxf(sqrtf(tot), 1e-12f);
  const float4 g = *(const float4*)(gamma + tid * 4);
  float o0 = v.x*scale*g.x, o1 = v.y*scale*g.y, o2 = v.z*scale*g.z, o3 = v.w*scale*g.w;
  size_t p = (size_t)row * DMODEL + tid * 4;
  if (OUT_BF16) {
    bf16* ob = (bf16*)out;
    ob[p+0] = (bf16)o0; ob[p+1] = (bf16)o1; ob[p+2] = (bf16)o2; ob[p+3] = (bf16)o3;
  } else {
    *(float4*)((float*)out + p) = make_float4(o0, o1, o2, o3);
  }
}

// ---------------- GEMM: C(MxN) = A(MxK) @ W(NxK)^T + bias [+ res] ----------------
// Round-4 core (runtime dims, no unroll of K loop) + bijective XCD-chunked
// block swizzle (T1): all blocks of one XCD share a contiguous panel range.
// CHUNK_M=false: XCD owns contiguous n-range (use when W > A);
// CHUNK_M=true : XCD owns contiguous m-range (use when A >= W).
// EPI: 0 = bf16 out, 1 = f32 out + residual add, 2 = fused GEGLU.
template<int TN, int EPI, bool CHUNK_M>
__global__ __launch_bounds__(256) void gemm_bt(const bf16* __restrict__ A,
    const bf16* __restrict__ Bw, const float* __restrict__ bias,
    const float* __restrict__ res, void* __restrict__ Cout,
    int M_, int N_, int K_) {
  constexpr int NFR = TN / 32;
  constexpr int BCH = TN / 32;
  __shared__ __attribute__((aligned(16))) bf16 As[2][128 * 64];
  __shared__ __attribute__((aligned(16))) bf16 Bs[2][TN * 64];
  const int tid  = threadIdx.x;
  const int lane = tid & 63;
  const int wid  = tid >> 6;
  const int wr = wid >> 1, wc = wid & 1;

  // XCD-chunked bijective swizzle (grids here are divisible by 8)
  const int gx = gridDim.x, gy = gridDim.y;
  const int nwg = gx * gy;
  int bid = blockIdx.y * gx + blockIdx.x;
  int swz = bid;
  if ((nwg & 7) == 0) swz = (bid & 7) * (nwg >> 3) + (bid >> 3);
  int mIdx, nIdx;
  if (CHUNK_M) { nIdx = swz % gx; mIdx = swz / gx; }   // contiguous m per XCD
  else         { mIdx = swz % gy; nIdx = swz / gy; }   // contiguous n per XCD
  const int m0 = mIdx * 128;
  const int n0 = nIdx * TN;

  const int q = lane & 15, G = lane >> 4;
  const int s7 = q & 7;                       // fragment-row & 7
  const int srow = tid >> 3;                  // staging row within 32-row slab
  const int scol = ((tid & 7) ^ (srow & 7)) << 3;  // pre-swizzled source col

  f32x4 acc[4][NFR] = {};
  const int nk = K_ >> 6;

  auto stage = [&](int buf, int kt) {
    const int k0 = kt << 6;
    #pragma unroll
    for (int j = 0; j < 4; ++j) {
      gload_lds16(A + (size_t)(m0 + j*32 + srow) * K_ + k0 + scol,
                  &As[buf][(j * 256 + wid * 64) << 3]);
    }
    #pragma unroll
    for (int j = 0; j < BCH; ++j) {
      gload_lds16(Bw + (size_t)(n0 + j*32 + srow) * K_ + k0 + scol,
                  &Bs[buf][(j * 256 + wid * 64) << 3]);
    }
  };

  stage(0, 0);
  asm volatile("s_waitcnt vmcnt(0)" ::: "memory");
  __syncthreads();

  int cur = 0;
  for (int kt = 0; kt < nk; ++kt) {
    if (kt + 1 < nk) stage(cur ^ 1, kt + 1);
    #pragma unroll
    for (int kk = 0; kk < 2; ++kk) {
      const int c0 = kk * 4 + G;
      bf16x8 af[4], bfr[NFR];
      #pragma unroll
      for (int m = 0; m < 4; ++m)
        af[m] = *(const bf16x8*)(&As[cur][(wr*64 + m*16 + q) * 64 + ((c0 ^ s7) << 3)]);
      #pragma unroll
      for (int n = 0; n < NFR; ++n)
        bfr[n] = *(const bf16x8*)(&Bs[cur][(wc*(TN/2) + n*16 + q) * 64 + ((c0 ^ s7) << 3)]);
      #pragma unroll
      for (int m = 0; m < 4; ++m)
        #pragma unroll
        for (int n = 0; n < NFR; ++n)
          acc[m][n] = mfma16(af[m], bfr[n], acc[m][n]);
    }
    asm volatile("s_waitcnt vmcnt(0)" ::: "memory");
    __syncthreads();
    cur ^= 1;
  }

  const int rb = G << 2;
  const int cl = q;
  if (EPI == 2) {
    #pragma unroll
    for (int m = 0; m < 4; ++m) {
      #pragma unroll
      for (int np = 0; np < NFR/2; ++np) {
        int ca = n0 + wc*(TN/2) + (2*np)*16 + cl;
        int cg = ca + 16;
        float ba = bias[ca], bg = bias[cg];
        int colo = ((ca >> 5) << 4) + cl;
        #pragma unroll
        for (int r = 0; r < 4; ++r) {
          int row = m0 + wr*64 + m*16 + rb + r;
          float av = acc[m][2*np][r] + ba;
          float gv = acc[m][2*np+1][r] + bg;
          float gl = 0.5f * gv * (1.f + erff(gv * 0.70710678118654752f));
          ((bf16*)Cout)[(size_t)row * (N_ >> 1) + colo] = (bf16)(av * gl);
        }
      }
    }
  } else {
    #pragma unroll
    for (int m = 0; m < 4; ++m) {
      #pragma unroll
      for (int n = 0; n < NFR; ++n) {
        int col = n0 + wc*(TN/2) + n*16 + cl;
        float bv = bias[col];
        #pragma unroll
        for (int r = 0; r < 4; ++r) {
          int row = m0 + wr*64 + m*16 + rb + r;
          float v = acc[m][n][r] + bv;
          size_t p = (size_t)row * N_ + col;
          if (EPI == 1) ((float*)Cout)[p] = v + res[p];
          else          ((bf16*)Cout)[p] = (bf16)v;
        }
      }
    }
  }
}

// ---------------- Flash attention, split-KV=2, ALiBi, KVBLK=64 ----------------
__global__ __launch_bounds__(256) void attn_kernel(const bf16* __restrict__ qkv,
    const float* __restrict__ slopes, float* __restrict__ Opart, float* __restrict__ ml) {
  const int tid = threadIdx.x, lane = tid & 63, wid = tid >> 6;
  const int bh = blockIdx.y;
  const int b = bh >> 4, h = bh & 15;
  const int kvz = blockIdx.z;
  const int kv0 = kvz * (LSEQ / NSPLIT);
  const float slope2 = slopes[h] * LOG2E;
  const float SC = 0.125f * LOG2E;
  const int qw = blockIdx.x * 64 + wid * 16;

  __shared__ __attribute__((aligned(16))) bf16     Kt[64 * 72];
  __shared__ __attribute__((aligned(16))) uint32_t V32[64 * 36];
  __shared__ __attribute__((aligned(16))) uint32_t Pl32[4][16 * 36];

  const size_t rs = 3 * DMODEL;
  const size_t base = (size_t)b * LSEQ * rs;

  bf16x8 qf[2];
  {
    const bf16* p = qkv + base + (size_t)(qw + (lane & 15)) * rs + h * HDIM + ((lane >> 4) << 3);
    qf[0] = *(const bf16x8*)p;
    qf[1] = *(const bf16x8*)(p + 32);
  }

  f32x4 accO[4] = {};
  float mrow[4], lrow[4];
  #pragma unroll
  for (int r = 0; r < 4; ++r) { mrow[r] = -1e30f; lrow[r] = 0.f; }

  const int trow = tid >> 2;
  const int tcol = (tid & 3) << 4;

  bf16x8 kreg0, kreg1, vreg0, vreg1;
  {
    const bf16* kp = qkv + base + (size_t)(kv0 + trow) * rs + DMODEL + h * HDIM + tcol;
    kreg0 = *(const bf16x8*)kp; kreg1 = *(const bf16x8*)(kp + 8);
    const bf16* vp = qkv + base + (size_t)(kv0 + trow) * rs + 2 * DMODEL + h * HDIM + tcol;
    vreg0 = *(const bf16x8*)vp; vreg1 = *(const bf16x8*)(vp + 8);
  }

  uint32_t* P32w = &Pl32[wid][0];
  const int q = lane & 15, G = lane >> 4;

  for (int kv = kv0; kv < kv0 + LSEQ / NSPLIT; kv += 64) {
    __syncthreads();
    *(bf16x8*)(Kt + trow * 72 + tcol)     = kreg0;
    *(bf16x8*)(Kt + trow * 72 + tcol + 8) = kreg1;
    {
      u32x4 va = __builtin_bit_cast(u32x4, vreg0);
      u32x4 vb = __builtin_bit_cast(u32x4, vreg1);
      u32x4 pa, pb;
      #pragma unroll
      for (int i = 0; i < 4; ++i) {
        pa[i] = (uint32_t)__shfl_xor((int)va[i], 4);
        pb[i] = (uint32_t)__shfl_xor((int)vb[i], 4);
      }
      const bool oddk = (trow & 1);
      const int d0 = tcol + (oddk ? 8 : 0);
      u32x4 m = oddk ? vb : va;
      u32x4 oo = oddk ? pb : pa;
      const int kpair = trow >> 1;
      const int swz = kpair ^ ((d0 >> 3) << 1);
      #pragma unroll
      for (int i = 0; i < 4; ++i) {
        uint32_t lo = oddk ? oo[i] : m[i];
        uint32_t hi = oddk ? m[i] : oo[i];
        uint32_t w0 = (lo & 0xffffu) | (hi << 16);
        uint32_t w1 = (lo >> 16) | (hi & 0xffff0000u);
        V32[(d0 + 2*i)     * 36 + swz] = w0;
        V32[(d0 + 2*i + 1) * 36 + swz] = w1;
      }
    }
    __syncthreads();

    if (kv + 64 < kv0 + LSEQ / NSPLIT) {
      const bf16* kp = qkv + base + (size_t)(kv + 64 + trow) * rs + DMODEL + h * HDIM + tcol;
      kreg0 = *(const bf16x8*)kp; kreg1 = *(const bf16x8*)(kp + 8);
      const bf16* vp = qkv + base + (size_t)(kv + 64 + trow) * rs + 2 * DMODEL + h * HDIM + tcol;
      vreg0 = *(const bf16x8*)vp; vreg1 = *(const bf16x8*)(vp + 8);
    }

    f32x4 sacc[4] = {};
    __builtin_amdgcn_s_setprio(1);
    #pragma unroll
    for (int nt = 0; nt < 4; ++nt) {
      const bf16* kb = Kt + (nt * 16 + q) * 72 + (G << 3);
      sacc[nt] = mfma16(qf[0], *(const bf16x8*)kb, sacc[nt]);
      sacc[nt] = mfma16(qf[1], *(const bf16x8*)(kb + 32), sacc[nt]);
    }
    __builtin_amdgcn_s_setprio(0);

    float pv[4][4];
    #pragma unroll
    for (int r = 0; r < 4; ++r) {
      int qi = qw + (G << 2) + r;
      float vmax = -1e30f;
      #pragma unroll
      for (int nt = 0; nt < 4; ++nt) {
        int kj = kv + nt * 16 + q;
        float s = sacc[nt][r] * SC - slope2 * fabsf((float)(qi - kj));
        pv[nt][r] = s;
        vmax = fmaxf(vmax, s);
      }
      for (int m = 1; m < 16; m <<= 1) vmax = fmaxf(vmax, __shfl_xor(vmax, m));
      float newmax = fmaxf(mrow[r], vmax);
      float ef = exp2f(mrow[r] - newmax);
      float rsum = 0.f;
      #pragma unroll
      for (int nt = 0; nt < 4; ++nt) {
        float p = exp2f(pv[nt][r] - newmax);
        pv[nt][r] = p;
        rsum += p;
      }
      for (int m = 1; m < 16; m <<= 1) rsum += __shfl_xor(rsum, m);
      lrow[r] = lrow[r] * ef + rsum;
      mrow[r] = newmax;
      #pragma unroll
      for (int dn = 0; dn < 4; ++dn) accO[dn][r] *= ef;
    }

    #pragma unroll
    for (int nt = 0; nt < 4; ++nt) {
      #pragma unroll
      for (int r = 0; r < 4; ++r) {
        float other = __shfl_xor(pv[nt][r], 1);
        if (!(lane & 1)) {
          uint32_t w;
          asm("v_cvt_pk_bf16_f32 %0, %1, %2" : "=v"(w) : "v"(pv[nt][r]), "v"(other));
          int prow = (G << 2) + r;
          int col2 = nt * 8 + (q >> 1);
          P32w[prow * 36 + (col2 ^ ((prow & 7) << 1))] = w;
        }
      }
    }
    asm volatile("s_waitcnt lgkmcnt(0)" ::: "memory");

    __builtin_amdgcn_s_setprio(1);
    #pragma unroll
    for (int chunk = 0; chunk < 2; ++chunk) {
      u32x4 praw = *(const u32x4*)(P32w + q * 36 + chunk * 16 + 4 * (G ^ ((q >> 1) & 3)));
      if (q & 1) praw = __builtin_shufflevector(praw, praw, 2, 3, 0, 1);
      bf16x8 pf = __builtin_bit_cast(bf16x8, praw);
      #pragma unroll
      for (int dn = 0; dn < 4; ++dn) {
        const int d = dn * 16 + q;
        u32x4 raw = *(const u32x4*)(V32 + d * 36 + chunk * 16 + 4 * (G ^ dn));
        if ((lane >> 3) & 1) raw = __builtin_shufflevector(raw, raw, 2, 3, 0, 1);
        bf16x8 vf = __builtin_bit_cast(bf16x8, raw);
        accO[dn] = mfma16(pf, vf, accO[dn]);
      }
    }
    __builtin_amdgcn_s_setprio(0);
  }

  #pragma unroll
  for (int r = 0; r < 4; ++r) {
    int qr = qw + (G << 2) + r;
    size_t obase = ((size_t)(kvz * 32 + bh) * LSEQ + qr) * HDIM;
    #pragma unroll
    for (int dn = 0; dn < 4; ++dn)
      Opart[obase + dn * 16 + q] = accO[dn][r];
    if (q == 0) {
      size_t mb = ((size_t)(kvz * 32 + bh) * LSEQ + qr) * 2;
      ml[mb]     = mrow[r];
      ml[mb + 1] = lrow[r];
    }
  }
}

// combine NSPLIT kv-parts
__global__ __launch_bounds__(256) void attn_combine(const float* __restrict__ Opart,
    const float* __restrict__ ml, bf16* __restrict__ o) {
  int idx = blockIdx.x * 256 + threadIdx.x;
  int bh = idx >> 14;
  int rem = idx & 16383;
  int qr = rem >> 4;
  int d4 = (rem & 15) << 2;
  float mz[NSPLIT], lz[NSPLIT];
  float m = -1e30f;
  #pragma unroll
  for (int z = 0; z < NSPLIT; ++z) {
    size_t rz = ((size_t)(z * 32 + bh) * LSEQ + qr) * 2;
    mz[z] = ml[rz]; lz[z] = ml[rz + 1];
    m = fmaxf(m, mz[z]);
  }
  float wz[NSPLIT];
  float l = 0.f;
  #pragma unroll
  for (int z = 0; z < NSPLIT; ++z) { wz[z] = exp2f(mz[z] - m); l += lz[z] * wz[z]; }
  float inv = 1.f / l;
  float ax = 0, ay = 0, az = 0, aw = 0;
  #pragma unroll
  for (int z = 0; z < NSPLIT; ++z) {
    size_t rz = (size_t)(z * 32 + bh) * LSEQ + qr;
    float4 ov = *(const float4*)(Opart + rz * HDIM + d4);
    ax += ov.x * wz[z]; ay += ov.y * wz[z]; az += ov.z * wz[z]; aw += ov.w * wz[z];
  }
  int b = bh >> 4, h = bh & 15;
  bf16* op = o + ((size_t)(b * LSEQ + qr) * DMODEL + h * HDIM + d4);
  op[0] = (bf16)(ax * inv);
  op[1] = (bf16)(ay * inv);
  op[2] = (bf16)(az * inv);
  op[3] = (bf16)(aw * inv);
}

// ---------------- host ----------------
extern "C" void kernel_launch(void* const* d_in, const int* in_sizes, int n_in,
                              void* d_out, int out_size, void* d_ws, size_t ws_size,
                              hipStream_t stream) {
  const float* x_in      = (const float*)d_in[0];
  const float* slopes    = (const float*)d_in[1];
  const float* g_attn    = (const float*)d_in[2];
  const float* w_in      = (const float*)d_in[3];
  const float* b_in      = (const float*)d_in[4];
  const float* w_out     = (const float*)d_in[5];
  const float* b_out     = (const float*)d_in[6];
  const float* g_ff      = (const float*)d_in[7];
  const float* w1        = (const float*)d_in[8];
  const float* b1        = (const float*)d_in[9];
  const float* w2        = (const float*)d_in[10];
  const float* b2        = (const float*)d_in[11];
  const float* g_final   = (const float*)d_in[12];

  char* p = (char*)d_ws;
  float* xw   = (float*)p;              p += (size_t)MROWS * DMODEL * 4;
  bf16* abuf  = (bf16*)p;               p += (size_t)MROWS * DMODEL * 2;
  bf16* qkvb  = (bf16*)p;               p += (size_t)MROWS * 3 * DMODEL * 2;
  bf16* obuf  = (bf16*)p;               p += (size_t)MROWS * DMODEL * 2;
  bf16* gbuf  = (bf16*)p;               p += (size_t)MROWS * INNERP * 2;
  float* Opart = (float*)p;             p += (size_t)NSPLIT * 32 * LSEQ * HDIM * 4;
  float* mlb   = (float*)p;             p += (size_t)NSPLIT * 32 * LSEQ * 2 * 4;
  bf16* w_in_b  = (bf16*)p;             p += (size_t)DEPTH * 3 * DMODEL * DMODEL * 2;
  bf16* w_out_b = (bf16*)p;             p += (size_t)DEPTH * DMODEL * DMODEL * 2;
  bf16* w1p     = (bf16*)p;             p += (size_t)DEPTH * N1P * DMODEL * 2;
  bf16* w2p     = (bf16*)p;             p += (size_t)DEPTH * DMODEL * INNERP * 2;
  float* b1p    = (float*)p;            p += (size_t)DEPTH * N1P * 4;

  hipMemcpyAsync(xw, x_in, (size_t)MROWS * DMODEL * 4, hipMemcpyDeviceToDevice, stream);

  conv_bf16_kernel<<<6144, 256, 0, stream>>>(w_in, w_in_b, (size_t)DEPTH * 3 * DMODEL * DMODEL);
  conv_bf16_kernel<<<2048, 256, 0, stream>>>(w_out, w_out_b, (size_t)DEPTH * DMODEL * DMODEL);
  conv_w1_kernel<<<11008, 256, 0, stream>>>(w1, w1p);
  conv_b1_kernel<<<86, 256, 0, stream>>>(b1, b1p);
  conv_w2_kernel<<<5504, 256, 0, stream>>>(w2, w2p);

  for (int i = 0; i < DEPTH; ++i) {
    rmsnorm_kernel<true><<<MROWS, 256, 0, stream>>>(xw, g_attn + i * DMODEL, abuf);
    gemm_bt<64, 0, false><<<dim3(48, 16), 256, 0, stream>>>(
        abuf, w_in_b + (size_t)i * 3 * DMODEL * DMODEL, b_in + i * 3 * DMODEL,
        nullptr, qkvb, MROWS, 3 * DMODEL, DMODEL);
    attn_kernel<<<dim3(16, 32, NSPLIT), 256, 0, stream>>>(qkvb, slopes, Opart, mlb);
    attn_combine<<<2048, 256, 0, stream>>>(Opart, mlb, obuf);
    gemm_bt<64, 1, true><<<dim3(16, 16), 256, 0, stream>>>(
        obuf, w_out_b + (size_t)i * DMODEL * DMODEL, b_out + i * DMODEL,
        xw, xw, MROWS, DMODEL, DMODEL);
    rmsnorm_kernel<true><<<MROWS, 256, 0, stream>>>(xw, g_ff + i * DMODEL, abuf);
    gemm_bt<128, 2, false><<<dim3(43, 16), 256, 0, stream>>>(
        abuf, w1p + (size_t)i * N1P * DMODEL, b1p + i * N1P,
        nullptr, gbuf, MROWS, N1P, DMODEL);
    gemm_bt<64, 1, true><<<dim3(16, 16), 256, 0, stream>>>(
        gbuf, w2p + (size_t)i * DMODEL * INNERP, b2 + i * DMODEL,
        xw, xw, MROWS, DMODEL, INNERP);
  }
  rmsnorm_kernel<false><<<MROWS, 256, 0, stream>>>(xw, g_final, d_out);
}

// Round 7
// 794.453 us; speedup vs baseline: 1.1585x; 1.0658x over previous
//
#include <hip/hip_runtime.h>

#define DEPTH   4
#define BSZ     2
#define LSEQ    1024
#define DMODEL  1024
#define NHEAD   16
#define HDIM    64
#define MROWS   (BSZ*LSEQ)    // 2048
#define INNER   2730
#define INNERP  2752
#define N1      (2*INNER)     // 5460
#define N1P     (2*INNERP)    // 5504
#define LOG2E   1.4426950408889634f
#define NSPLIT  2

typedef __bf16 bf16;
typedef bf16  bf16x8 __attribute__((ext_vector_type(8)));
typedef float f32x4  __attribute__((ext_vector_type(4)));
typedef uint32_t u32x4 __attribute__((ext_vector_type(4)));

__device__ inline f32x4 mfma16(bf16x8 a, bf16x8 b, f32x4 c) {
  return __builtin_amdgcn_mfma_f32_16x16x32_bf16(a, b, c, 0, 0, 0);
}

__device__ inline void gload_lds16(const void* g, void* l) {
  __builtin_amdgcn_global_load_lds(
      (const __attribute__((address_space(1))) void*)g,
      (__attribute__((address_space(3))) void*)l, 16, 0, 0);
}

// ---------------- weight conversion (vectorized stores) ----------------
__global__ void conv_bf16_kernel(const float* __restrict__ src, bf16* __restrict__ dst, size_t n) {
  size_t i = ((size_t)blockIdx.x * 256 + threadIdx.x) * 8;
  if (i >= n) return;
  float4 v0 = *(const float4*)(src + i);
  float4 v1 = *(const float4*)(src + i + 4);
  bf16x8 o = { (bf16)v0.x,(bf16)v0.y,(bf16)v0.z,(bf16)v0.w,
               (bf16)v1.x,(bf16)v1.y,(bf16)v1.z,(bf16)v1.w };
  *(bf16x8*)(dst + i) = o;
}

// ff_w1 (DEPTH,5460,1024) -> padded interleaved (DEPTH,5504,1024):
// padded row rp: p=rp>>4, w=rp&15, col=(p>>1)*16+w; even p -> a-row col,
// odd p -> gate-row INNER+col; col>=INNER -> zero.
__global__ void conv_w1_kernel(const float* __restrict__ src, bf16* __restrict__ dst) {
  size_t i = ((size_t)blockIdx.x * 256 + threadIdx.x) * 8;
  const size_t tot = (size_t)DEPTH * N1P * DMODEL;
  if (i >= tot) return;
  int d  = (int)(i / ((size_t)N1P * DMODEL));
  int rem = (int)(i % ((size_t)N1P * DMODEL));
  int rp = rem / DMODEL, k = rem % DMODEL;
  int p2 = rp >> 4, w = rp & 15;
  int col = ((p2 >> 1) << 4) + w;
  bf16x8 o;
  if (col >= INNER) {
    o = (bf16x8)(bf16)0.f;
  } else {
    int rs = (p2 & 1) ? (INNER + col) : col;
    const float* s = src + ((size_t)d * N1 + rs) * DMODEL + k;
    float4 v0 = *(const float4*)s;
    float4 v1 = *(const float4*)(s + 4);
    o = bf16x8{ (bf16)v0.x,(bf16)v0.y,(bf16)v0.z,(bf16)v0.w,
                (bf16)v1.x,(bf16)v1.y,(bf16)v1.z,(bf16)v1.w };
  }
  *(bf16x8*)(dst + i) = o;
}

__global__ void conv_b1_kernel(const float* __restrict__ src, float* __restrict__ dst) {
  int i = blockIdx.x * 256 + threadIdx.x;
  if (i >= DEPTH * N1P) return;
  int d = i / N1P, rp = i % N1P;
  int p2 = rp >> 4, w = rp & 15;
  int col = ((p2 >> 1) << 4) + w;
  float v = 0.f;
  if (col < INNER) v = src[d * N1 + ((p2 & 1) ? (INNER + col) : col)];
  dst[i] = v;
}

__global__ void conv_w2_kernel(const float* __restrict__ src, bf16* __restrict__ dst) {
  size_t i = ((size_t)blockIdx.x * 256 + threadIdx.x) * 8;
  const size_t tot = (size_t)DEPTH * DMODEL * INNERP;
  if (i >= tot) return;
  size_t dn = i / INNERP;
  int kp = (int)(i % INNERP);
  const float* s = src + dn * INNER;
  bf16x8 o;
  #pragma unroll
  for (int j = 0; j < 8; ++j) {
    int k = kp + j;
    o[j] = (k < INNER) ? (bf16)s[k] : (bf16)0.f;
  }
  *(bf16x8*)(dst + i) = o;
}

// ---------------- RMSNorm ----------------
template<bool OUT_BF16>
__global__ __launch_bounds__(256) void rmsnorm_kernel(const float* __restrict__ x,
    const float* __restrict__ gamma, void* __restrict__ out) {
  const int row = blockIdx.x;
  const int tid = threadIdx.x;
  const float4 v = *(const float4*)(x + (size_t)row * DMODEL + tid * 4);
  float ss = v.x*v.x + v.y*v.y + v.z*v.z + v.w*v.w;
  for (int m = 1; m < 64; m <<= 1) ss += __shfl_xor(ss, m);
  __shared__ float ws4[4];
  if ((tid & 63) == 0) ws4[tid >> 6] = ss;
  __syncthreads();
  float tot = ws4[0] + ws4[1] + ws4[2] + ws4[3];
  float scale = 32.0f / fmaxf(sqrtf(tot), 1e-12f);
  const float4 g = *(const float4*)(gamma + tid * 4);
  float o0 = v.x*scale*g.x, o1 = v.y*scale*g.y, o2 = v.z*scale*g.z, o3 = v.w*scale*g.w;
  size_t p = (size_t)row * DMODEL + tid * 4;
  if (OUT_BF16) {
    bf16* ob = (bf16*)out;
    ob[p+0] = (bf16)o0; ob[p+1] = (bf16)o1; ob[p+2] = (bf16)o2; ob[p+3] = (bf16)o3;
  } else {
    *(float4*)((float*)out + p) = make_float4(o0, o1, o2, o3);
  }
}

// ---------------- GEMM: C(MxN) = A(MxK) @ W(NxK)^T ----------------
// Round-4 core + XCD-chunked swizzle + optional split-K over blockIdx.z.
// Kstr = row stride of A and W; z-slice covers nk steps starting at kOff.
// EPI: 0 = bf16 out + bias; 2 = fused GEGLU + bias; 3 = f32 atomicAdd
// partial into Cout (residual accumulator), bias added by z==0 only.
template<int TN, int EPI, bool CHUNK_M>
__global__ __launch_bounds__(256) void gemm_bt(const bf16* __restrict__ A,
    const bf16* __restrict__ Bw, const float* __restrict__ bias,
    void* __restrict__ Cout, int M_, int N_, int Kstr, int nk0, int nkTot) {
  constexpr int NFR = TN / 32;
  constexpr int BCH = TN / 32;
  __shared__ __attribute__((aligned(16))) bf16 As[2][128 * 64];
  __shared__ __attribute__((aligned(16))) bf16 Bs[2][TN * 64];
  const int tid  = threadIdx.x;
  const int lane = tid & 63;
  const int wid  = tid >> 6;
  const int wr = wid >> 1, wc = wid & 1;

  const int z = blockIdx.z;
  const int nk  = z ? (nkTot - nk0) : nk0;
  const int kOff = z * (nk0 << 6);

  // XCD-chunked bijective swizzle (per z-plane; planes here are /8)
  const int gx = gridDim.x, gy = gridDim.y;
  const int nwg = gx * gy;
  int bid = blockIdx.y * gx + blockIdx.x;
  int swz = bid;
  if ((nwg & 7) == 0) swz = (bid & 7) * (nwg >> 3) + (bid >> 3);
  int mIdx, nIdx;
  if (CHUNK_M) { nIdx = swz % gx; mIdx = swz / gx; }
  else         { mIdx = swz % gy; nIdx = swz / gy; }
  const int m0 = mIdx * 128;
  const int n0 = nIdx * TN;

  const int q = lane & 15, G = lane >> 4;
  const int s7 = q & 7;
  const int srow = tid >> 3;
  const int scol = ((tid & 7) ^ (srow & 7)) << 3;

  f32x4 acc[4][NFR] = {};

  auto stage = [&](int buf, int kt) {
    const int k0 = kOff + (kt << 6);
    #pragma unroll
    for (int j = 0; j < 4; ++j) {
      gload_lds16(A + (size_t)(m0 + j*32 + srow) * Kstr + k0 + scol,
                  &As[buf][(j * 256 + wid * 64) << 3]);
    }
    #pragma unroll
    for (int j = 0; j < BCH; ++j) {
      gload_lds16(Bw + (size_t)(n0 + j*32 + srow) * Kstr + k0 + scol,
                  &Bs[buf][(j * 256 + wid * 64) << 3]);
    }
  };

  stage(0, 0);
  asm volatile("s_waitcnt vmcnt(0)" ::: "memory");
  __syncthreads();

  int cur = 0;
  for (int kt = 0; kt < nk; ++kt) {
    if (kt + 1 < nk) stage(cur ^ 1, kt + 1);
    #pragma unroll
    for (int kk = 0; kk < 2; ++kk) {
      const int c0 = kk * 4 + G;
      bf16x8 af[4], bfr[NFR];
      #pragma unroll
      for (int m = 0; m < 4; ++m)
        af[m] = *(const bf16x8*)(&As[cur][(wr*64 + m*16 + q) * 64 + ((c0 ^ s7) << 3)]);
      #pragma unroll
      for (int n = 0; n < NFR; ++n)
        bfr[n] = *(const bf16x8*)(&Bs[cur][(wc*(TN/2) + n*16 + q) * 64 + ((c0 ^ s7) << 3)]);
      #pragma unroll
      for (int m = 0; m < 4; ++m)
        #pragma unroll
        for (int n = 0; n < NFR; ++n)
          acc[m][n] = mfma16(af[m], bfr[n], acc[m][n]);
    }
    asm volatile("s_waitcnt vmcnt(0)" ::: "memory");
    __syncthreads();
    cur ^= 1;
  }

  const int rb = G << 2;
  const int cl = q;
  if (EPI == 2) {
    #pragma unroll
    for (int m = 0; m < 4; ++m) {
      #pragma unroll
      for (int np = 0; np < NFR/2; ++np) {
        int ca = n0 + wc*(TN/2) + (2*np)*16 + cl;
        int cg = ca + 16;
        float ba = bias[ca], bg = bias[cg];
        int colo = ((ca >> 5) << 4) + cl;
        #pragma unroll
        for (int r = 0; r < 4; ++r) {
          int row = m0 + wr*64 + m*16 + rb + r;
          float av = acc[m][2*np][r] + ba;
          float gv = acc[m][2*np+1][r] + bg;
          float gl = 0.5f * gv * (1.f + erff(gv * 0.70710678118654752f));
          ((bf16*)Cout)[(size_t)row * (N_ >> 1) + colo] = (bf16)(av * gl);
        }
      }
    }
  } else if (EPI == 3) {
    #pragma unroll
    for (int m = 0; m < 4; ++m) {
      #pragma unroll
      for (int n = 0; n < NFR; ++n) {
        int col = n0 + wc*(TN/2) + n*16 + cl;
        float bv = (z == 0) ? bias[col] : 0.f;
        #pragma unroll
        for (int r = 0; r < 4; ++r) {
          int row = m0 + wr*64 + m*16 + rb + r;
          atomicAdd((float*)Cout + (size_t)row * N_ + col, acc[m][n][r] + bv);
        }
      }
    }
  } else {
    #pragma unroll
    for (int m = 0; m < 4; ++m) {
      #pragma unroll
      for (int n = 0; n < NFR; ++n) {
        int col = n0 + wc*(TN/2) + n*16 + cl;
        float bv = bias[col];
        #pragma unroll
        for (int r = 0; r < 4; ++r) {
          int row = m0 + wr*64 + m*16 + rb + r;
          ((bf16*)Cout)[(size_t)row * N_ + col] = (bf16)(acc[m][n][r] + bv);
        }
      }
    }
  }
}

// ---------------- Flash attention, split-KV=2, ALiBi, KVBLK=64 ----------------
__global__ __launch_bounds__(256) void attn_kernel(const bf16* __restrict__ qkv,
    const float* __restrict__ slopes, float* __restrict__ Opart, float* __restrict__ ml) {
  const int tid = threadIdx.x, lane = tid & 63, wid = tid >> 6;
  const int bh = blockIdx.y;
  const int b = bh >> 4, h = bh & 15;
  const int kvz = blockIdx.z;
  const int kv0 = kvz * (LSEQ / NSPLIT);
  const float slope2 = slopes[h] * LOG2E;
  const float SC = 0.125f * LOG2E;
  const int qw = blockIdx.x * 64 + wid * 16;

  __shared__ __attribute__((aligned(16))) bf16     Kt[64 * 72];
  __shared__ __attribute__((aligned(16))) uint32_t V32[64 * 36];
  __shared__ __attribute__((aligned(16))) uint32_t Pl32[4][16 * 36];

  const size_t rs = 3 * DMODEL;
  const size_t base = (size_t)b * LSEQ * rs;

  bf16x8 qf[2];
  {
    const bf16* p = qkv + base + (size_t)(qw + (lane & 15)) * rs + h * HDIM + ((lane >> 4) << 3);
    qf[0] = *(const bf16x8*)p;
    qf[1] = *(const bf16x8*)(p + 32);
  }

  f32x4 accO[4] = {};
  float mrow[4], lrow[4];
  #pragma unroll
  for (int r = 0; r < 4; ++r) { mrow[r] = -1e30f; lrow[r] = 0.f; }

  const int trow = tid >> 2;
  const int tcol = (tid & 3) << 4;

  bf16x8 kreg0, kreg1, vreg0, vreg1;
  {
    const bf16* kp = qkv + base + (size_t)(kv0 + trow) * rs + DMODEL + h * HDIM + tcol;
    kreg0 = *(const bf16x8*)kp; kreg1 = *(const bf16x8*)(kp + 8);
    const bf16* vp = qkv + base + (size_t)(kv0 + trow) * rs + 2 * DMODEL + h * HDIM + tcol;
    vreg0 = *(const bf16x8*)vp; vreg1 = *(const bf16x8*)(vp + 8);
  }

  uint32_t* P32w = &Pl32[wid][0];
  const int q = lane & 15, G = lane >> 4;

  for (int kv = kv0; kv < kv0 + LSEQ / NSPLIT; kv += 64) {
    __syncthreads();
    *(bf16x8*)(Kt + trow * 72 + tcol)     = kreg0;
    *(bf16x8*)(Kt + trow * 72 + tcol + 8) = kreg1;
    {
      u32x4 va = __builtin_bit_cast(u32x4, vreg0);
      u32x4 vb = __builtin_bit_cast(u32x4, vreg1);
      u32x4 pa, pb;
      #pragma unroll
      for (int i = 0; i < 4; ++i) {
        pa[i] = (uint32_t)__shfl_xor((int)va[i], 4);
        pb[i] = (uint32_t)__shfl_xor((int)vb[i], 4);
      }
      const bool oddk = (trow & 1);
      const int d0 = tcol + (oddk ? 8 : 0);
      u32x4 m = oddk ? vb : va;
      u32x4 oo = oddk ? pb : pa;
      const int kpair = trow >> 1;
      const int swz = kpair ^ ((d0 >> 3) << 1);
      #pragma unroll
      for (int i = 0; i < 4; ++i) {
        uint32_t lo = oddk ? oo[i] : m[i];
        uint32_t hi = oddk ? m[i] : oo[i];
        uint32_t w0 = (lo & 0xffffu) | (hi << 16);
        uint32_t w1 = (lo >> 16) | (hi & 0xffff0000u);
        V32[(d0 + 2*i)     * 36 + swz] = w0;
        V32[(d0 + 2*i + 1) * 36 + swz] = w1;
      }
    }
    __syncthreads();

    if (kv + 64 < kv0 + LSEQ / NSPLIT) {
      const bf16* kp = qkv + base + (size_t)(kv + 64 + trow) * rs + DMODEL + h * HDIM + tcol;
      kreg0 = *(const bf16x8*)kp; kreg1 = *(const bf16x8*)(kp + 8);
      const bf16* vp = qkv + base + (size_t)(kv + 64 + trow) * rs + 2 * DMODEL + h * HDIM + tcol;
      vreg0 = *(const bf16x8*)vp; vreg1 = *(const bf16x8*)(vp + 8);
    }

    f32x4 sacc[4] = {};
    __builtin_amdgcn_s_setprio(1);
    #pragma unroll
    for (int nt = 0; nt < 4; ++nt) {
      const bf16* kb = Kt + (nt * 16 + q) * 72 + (G << 3);
      sacc[nt] = mfma16(qf[0], *(const bf16x8*)kb, sacc[nt]);
      sacc[nt] = mfma16(qf[1], *(const bf16x8*)(kb + 32), sacc[nt]);
    }
    __builtin_amdgcn_s_setprio(0);

    float pv[4][4];
    #pragma unroll
    for (int r = 0; r < 4; ++r) {
      int qi = qw + (G << 2) + r;
      float vmax = -1e30f;
      #pragma unroll
      for (int nt = 0; nt < 4; ++nt) {
        int kj = kv + nt * 16 + q;
        float s = sacc[nt][r] * SC - slope2 * fabsf((float)(qi - kj));
        pv[nt][r] = s;
        vmax = fmaxf(vmax, s);
      }
      for (int m = 1; m < 16; m <<= 1) vmax = fmaxf(vmax, __shfl_xor(vmax, m));
      float newmax = fmaxf(mrow[r], vmax);
      float ef = exp2f(mrow[r] - newmax);
      float rsum = 0.f;
      #pragma unroll
      for (int nt = 0; nt < 4; ++nt) {
        float p = exp2f(pv[nt][r] - newmax);
        pv[nt][r] = p;
        rsum += p;
      }
      for (int m = 1; m < 16; m <<= 1) rsum += __shfl_xor(rsum, m);
      lrow[r] = lrow[r] * ef + rsum;
      mrow[r] = newmax;
      #pragma unroll
      for (int dn = 0; dn < 4; ++dn) accO[dn][r] *= ef;
    }

    #pragma unroll
    for (int nt = 0; nt < 4; ++nt) {
      #pragma unroll
      for (int r = 0; r < 4; ++r) {
        float other = __shfl_xor(pv[nt][r], 1);
        if (!(lane & 1)) {
          uint32_t w;
          asm("v_cvt_pk_bf16_f32 %0, %1, %2" : "=v"(w) : "v"(pv[nt][r]), "v"(other));
          int prow = (G << 2) + r;
          int col2 = nt * 8 + (q >> 1);
          P32w[prow * 36 + (col2 ^ ((prow & 7) << 1))] = w;
        }
      }
    }
    asm volatile("s_waitcnt lgkmcnt(0)" ::: "memory");

    __builtin_amdgcn_s_setprio(1);
    #pragma unroll
    for (int chunk = 0; chunk < 2; ++chunk) {
      u32x4 praw = *(const u32x4*)(P32w + q * 36 + chunk * 16 + 4 * (G ^ ((q >> 1) & 3)));
      if (q & 1) praw = __builtin_shufflevector(praw, praw, 2, 3, 0, 1);
      bf16x8 pf = __builtin_bit_cast(bf16x8, praw);
      #pragma unroll
      for (int dn = 0; dn < 4; ++dn) {
        const int d = dn * 16 + q;
        u32x4 raw = *(const u32x4*)(V32 + d * 36 + chunk * 16 + 4 * (G ^ dn));
        if ((lane >> 3) & 1) raw = __builtin_shufflevector(raw, raw, 2, 3, 0, 1);
        bf16x8 vf = __builtin_bit_cast(bf16x8, raw);
        accO[dn] = mfma16(pf, vf, accO[dn]);
      }
    }
    __builtin_amdgcn_s_setprio(0);
  }

  #pragma unroll
  for (int r = 0; r < 4; ++r) {
    int qr = qw + (G << 2) + r;
    size_t obase = ((size_t)(kvz * 32 + bh) * LSEQ + qr) * HDIM;
    #pragma unroll
    for (int dn = 0; dn < 4; ++dn)
      Opart[obase + dn * 16 + q] = accO[dn][r];
    if (q == 0) {
      size_t mb = ((size_t)(kvz * 32 + bh) * LSEQ + qr) * 2;
      ml[mb]     = mrow[r];
      ml[mb + 1] = lrow[r];
    }
  }
}

// combine NSPLIT kv-parts
__global__ __launch_bounds__(256) void attn_combine(const float* __restrict__ Opart,
    const float* __restrict__ ml, bf16* __restrict__ o) {
  int idx = blockIdx.x * 256 + threadIdx.x;
  int bh = idx >> 14;
  int rem = idx & 16383;
  int qr = rem >> 4;
  int d4 = (rem & 15) << 2;
  float mz[NSPLIT], lz[NSPLIT];
  float m = -1e30f;
  #pragma unroll
  for (int z = 0; z < NSPLIT; ++z) {
    size_t rz = ((size_t)(z * 32 + bh) * LSEQ + qr) * 2;
    mz[z] = ml[rz]; lz[z] = ml[rz + 1];
    m = fmaxf(m, mz[z]);
  }
  float wz[NSPLIT];
  float l = 0.f;
  #pragma unroll
  for (int z = 0; z < NSPLIT; ++z) { wz[z] = exp2f(mz[z] - m); l += lz[z] * wz[z]; }
  float inv = 1.f / l;
  float ax = 0, ay = 0, az = 0, aw = 0;
  #pragma unroll
  for (int z = 0; z < NSPLIT; ++z) {
    size_t rz = (size_t)(z * 32 + bh) * LSEQ + qr;
    float4 ov = *(const float4*)(Opart + rz * HDIM + d4);
    ax += ov.x * wz[z]; ay += ov.y * wz[z]; az += ov.z * wz[z]; aw += ov.w * wz[z];
  }
  int b = bh >> 4, h = bh & 15;
  bf16* op = o + ((size_t)(b * LSEQ + qr) * DMODEL + h * HDIM + d4);
  op[0] = (bf16)(ax * inv);
  op[1] = (bf16)(ay * inv);
  op[2] = (bf16)(az * inv);
  op[3] = (bf16)(aw * inv);
}

// ---------------- host ----------------
extern "C" void kernel_launch(void* const* d_in, const int* in_sizes, int n_in,
                              void* d_out, int out_size, void* d_ws, size_t ws_size,
                              hipStream_t stream) {
  const float* x_in      = (const float*)d_in[0];
  const float* slopes    = (const float*)d_in[1];
  const float* g_attn    = (const float*)d_in[2];
  const float* w_in      = (const float*)d_in[3];
  const float* b_in      = (const float*)d_in[4];
  const float* w_out     = (const float*)d_in[5];
  const float* b_out     = (const float*)d_in[6];
  const float* g_ff      = (const float*)d_in[7];
  const float* w1        = (const float*)d_in[8];
  const float* b1        = (const float*)d_in[9];
  const float* w2        = (const float*)d_in[10];
  const float* b2        = (const float*)d_in[11];
  const float* g_final   = (const float*)d_in[12];

  char* p = (char*)d_ws;
  float* xw   = (float*)p;              p += (size_t)MROWS * DMODEL * 4;
  bf16* abuf  = (bf16*)p;               p += (size_t)MROWS * DMODEL * 2;
  bf16* qkvb  = (bf16*)p;               p += (size_t)MROWS * 3 * DMODEL * 2;
  bf16* obuf  = (bf16*)p;               p += (size_t)MROWS * DMODEL * 2;
  bf16* gbuf  = (bf16*)p;               p += (size_t)MROWS * INNERP * 2;
  float* Opart = (float*)p;             p += (size_t)NSPLIT * 32 * LSEQ * HDIM * 4;
  float* mlb   = (float*)p;             p += (size_t)NSPLIT * 32 * LSEQ * 2 * 4;
  bf16* w_in_b  = (bf16*)p;             p += (size_t)DEPTH * 3 * DMODEL * DMODEL * 2;
  bf16* w_out_b = (bf16*)p;             p += (size_t)DEPTH * DMODEL * DMODEL * 2;
  bf16* w1p     = (bf16*)p;             p += (size_t)DEPTH * N1P * DMODEL * 2;
  bf16* w2p     = (bf16*)p;             p += (size_t)DEPTH * DMODEL * INNERP * 2;
  float* b1p    = (float*)p;            p += (size_t)DEPTH * N1P * 4;

  hipMemcpyAsync(xw, x_in, (size_t)MROWS * DMODEL * 4, hipMemcpyDeviceToDevice, stream);

  conv_bf16_kernel<<<6144, 256, 0, stream>>>(w_in, w_in_b, (size_t)DEPTH * 3 * DMODEL * DMODEL);
  conv_bf16_kernel<<<2048, 256, 0, stream>>>(w_out, w_out_b, (size_t)DEPTH * DMODEL * DMODEL);
  conv_w1_kernel<<<11008, 256, 0, stream>>>(w1, w1p);
  conv_b1_kernel<<<86, 256, 0, stream>>>(b1, b1p);
  conv_w2_kernel<<<5504, 256, 0, stream>>>(w2, w2p);

  for (int i = 0; i < DEPTH; ++i) {
    rmsnorm_kernel<true><<<MROWS, 256, 0, stream>>>(xw, g_attn + i * DMODEL, abuf);
    // qkv: (M,N,K) = (2048, 3072, 1024), bf16 out
    gemm_bt<64, 0, false><<<dim3(48, 16), 256, 0, stream>>>(
        abuf, w_in_b + (size_t)i * 3 * DMODEL * DMODEL, b_in + i * 3 * DMODEL,
        qkvb, MROWS, 3 * DMODEL, DMODEL, 16, 16);
    attn_kernel<<<dim3(16, 32, NSPLIT), 256, 0, stream>>>(qkvb, slopes, Opart, mlb);
    attn_combine<<<2048, 256, 0, stream>>>(Opart, mlb, obuf);
    // out-proj: (2048, 1024, 1024), split-K=2, atomic into xw (residual)
    gemm_bt<64, 3, true><<<dim3(16, 16, 2), 256, 0, stream>>>(
        obuf, w_out_b + (size_t)i * DMODEL * DMODEL, b_out + i * DMODEL,
        xw, MROWS, DMODEL, DMODEL, 8, 16);
    rmsnorm_kernel<true><<<MROWS, 256, 0, stream>>>(xw, g_ff + i * DMODEL, abuf);
    // w1 + GEGLU: (2048, 5504, 1024) -> gbuf (2048 x 2752 bf16); TN=64 tile
    gemm_bt<64, 2, false><<<dim3(86, 16), 256, 0, stream>>>(
        abuf, w1p + (size_t)i * N1P * DMODEL, b1p + i * N1P,
        gbuf, MROWS, N1P, DMODEL, 16, 16);
    // w2: (2048, 1024, 2752), split-K=2 (22+21 steps), atomic into xw
    gemm_bt<64, 3, true><<<dim3(16, 16, 2), 256, 0, stream>>>(
        gbuf, w2p + (size_t)i * DMODEL * INNERP, b2 + i * DMODEL,
        xw, MROWS, DMODEL, INNERP, 22, 43);
  }
  rmsnorm_kernel<false><<<MROWS, 256, 0, stream>>>(xw, g_final, d_out);
}

// Round 8
// 700.969 us; speedup vs baseline: 1.3130x; 1.1334x over previous
//
#include <hip/hip_runtime.h>

#define DEPTH   4
#define BSZ     2
#define LSEQ    1024
#define DMODEL  1024
#define NHEAD   16
#define HDIM    64
#define MROWS   (BSZ*LSEQ)    // 2048
#define INNER   2730
#define INNERP  2752
#define N1      (2*INNER)     // 5460
#define N1P     (2*INNERP)    // 5504
#define LOG2E   1.4426950408889634f
#define NSPLIT  2

typedef __bf16 bf16;
typedef bf16  bf16x8 __attribute__((ext_vector_type(8)));
typedef float f32x4  __attribute__((ext_vector_type(4)));
typedef uint32_t u32x4 __attribute__((ext_vector_type(4)));

__device__ inline f32x4 mfma16(bf16x8 a, bf16x8 b, f32x4 c) {
  return __builtin_amdgcn_mfma_f32_16x16x32_bf16(a, b, c, 0, 0, 0);
}

__device__ inline void gload_lds16(const void* g, void* l) {
  __builtin_amdgcn_global_load_lds(
      (const __attribute__((address_space(1))) void*)g,
      (__attribute__((address_space(3))) void*)l, 16, 0, 0);
}

// ---------------- weight conversion (vectorized stores) ----------------
__global__ void conv_bf16_kernel(const float* __restrict__ src, bf16* __restrict__ dst, size_t n) {
  size_t i = ((size_t)blockIdx.x * 256 + threadIdx.x) * 8;
  if (i >= n) return;
  float4 v0 = *(const float4*)(src + i);
  float4 v1 = *(const float4*)(src + i + 4);
  bf16x8 o = { (bf16)v0.x,(bf16)v0.y,(bf16)v0.z,(bf16)v0.w,
               (bf16)v1.x,(bf16)v1.y,(bf16)v1.z,(bf16)v1.w };
  *(bf16x8*)(dst + i) = o;
}

// ff_w1 (DEPTH,5460,1024) -> padded interleaved (DEPTH,5504,1024):
// padded row rp: p=rp>>4, w=rp&15, col=(p>>1)*16+w; even p -> a-row col,
// odd p -> gate-row INNER+col; col>=INNER -> zero.
__global__ void conv_w1_kernel(const float* __restrict__ src, bf16* __restrict__ dst) {
  size_t i = ((size_t)blockIdx.x * 256 + threadIdx.x) * 8;
  const size_t tot = (size_t)DEPTH * N1P * DMODEL;
  if (i >= tot) return;
  int d  = (int)(i / ((size_t)N1P * DMODEL));
  int rem = (int)(i % ((size_t)N1P * DMODEL));
  int rp = rem / DMODEL, k = rem % DMODEL;
  int p2 = rp >> 4, w = rp & 15;
  int col = ((p2 >> 1) << 4) + w;
  bf16x8 o;
  if (col >= INNER) {
    o = (bf16x8)(bf16)0.f;
  } else {
    int rs = (p2 & 1) ? (INNER + col) : col;
    const float* s = src + ((size_t)d * N1 + rs) * DMODEL + k;
    float4 v0 = *(const float4*)s;
    float4 v1 = *(const float4*)(s + 4);
    o = bf16x8{ (bf16)v0.x,(bf16)v0.y,(bf16)v0.z,(bf16)v0.w,
                (bf16)v1.x,(bf16)v1.y,(bf16)v1.z,(bf16)v1.w };
  }
  *(bf16x8*)(dst + i) = o;
}

__global__ void conv_b1_kernel(const float* __restrict__ src, float* __restrict__ dst) {
  int i = blockIdx.x * 256 + threadIdx.x;
  if (i >= DEPTH * N1P) return;
  int d = i / N1P, rp = i % N1P;
  int p2 = rp >> 4, w = rp & 15;
  int col = ((p2 >> 1) << 4) + w;
  float v = 0.f;
  if (col < INNER) v = src[d * N1 + ((p2 & 1) ? (INNER + col) : col)];
  dst[i] = v;
}

__global__ void conv_w2_kernel(const float* __restrict__ src, bf16* __restrict__ dst) {
  size_t i = ((size_t)blockIdx.x * 256 + threadIdx.x) * 8;
  const size_t tot = (size_t)DEPTH * DMODEL * INNERP;
  if (i >= tot) return;
  size_t dn = i / INNERP;
  int kp = (int)(i % INNERP);
  const float* s = src + dn * INNER;
  bf16x8 o;
  #pragma unroll
  for (int j = 0; j < 8; ++j) {
    int k = kp + j;
    o[j] = (k < INNER) ? (bf16)s[k] : (bf16)0.f;
  }
  *(bf16x8*)(dst + i) = o;
}

// ---------------- RMSNorm ----------------
template<bool OUT_BF16>
__global__ __launch_bounds__(256) void rmsnorm_kernel(const float* __restrict__ x,
    const float* __restrict__ gamma, void* __restrict__ out) {
  const int row = blockIdx.x;
  const int tid = threadIdx.x;
  const float4 v = *(const float4*)(x + (size_t)row * DMODEL + tid * 4);
  float ss = v.x*v.x + v.y*v.y + v.z*v.z + v.w*v.w;
  for (int m = 1; m < 64; m <<= 1) ss += __shfl_xor(ss, m);
  __shared__ float ws4[4];
  if ((tid & 63) == 0) ws4[tid >> 6] = ss;
  __syncthreads();
  float tot = ws4[0] + ws4[1] + ws4[2] + ws4[3];
  float scale = 32.0f / fmaxf(sqrtf(tot), 1e-12f);
  const float4 g = *(const float4*)(gamma + tid * 4);
  float o0 = v.x*scale*g.x, o1 = v.y*scale*g.y, o2 = v.z*scale*g.z, o3 = v.w*scale*g.w;
  size_t p = (size_t)row * DMODEL + tid * 4;
  if (OUT_BF16) {
    bf16* ob = (bf16*)out;
    ob[p+0] = (bf16)o0; ob[p+1] = (bf16)o1; ob[p+2] = (bf16)o2; ob[p+3] = (bf16)o3;
  } else {
    *(float4*)((float*)out + p) = make_float4(o0, o1, o2, o3);
  }
}

// ---------------- GEMM: C(MxN) = A(MxK) @ W(NxK)^T ----------------
// Round-4 core + XCD-chunked swizzle + optional split-K over blockIdx.z.
// EPI: 0 = bf16 out + bias; 2 = fused GEGLU + bias; 3 = f32 atomicAdd
// partial into Cout (residual accumulator), bias added by z==0 only.
template<int TN, int EPI, bool CHUNK_M>
__global__ __launch_bounds__(256) void gemm_bt(const bf16* __restrict__ A,
    const bf16* __restrict__ Bw, const float* __restrict__ bias,
    void* __restrict__ Cout, int M_, int N_, int Kstr, int nk0, int nkTot) {
  constexpr int NFR = TN / 32;
  constexpr int BCH = TN / 32;
  __shared__ __attribute__((aligned(16))) bf16 As[2][128 * 64];
  __shared__ __attribute__((aligned(16))) bf16 Bs[2][TN * 64];
  const int tid  = threadIdx.x;
  const int lane = tid & 63;
  const int wid  = tid >> 6;
  const int wr = wid >> 1, wc = wid & 1;

  const int z = blockIdx.z;
  const int nk  = z ? (nkTot - nk0) : nk0;
  const int kOff = z * (nk0 << 6);

  const int gx = gridDim.x, gy = gridDim.y;
  const int nwg = gx * gy;
  int bid = blockIdx.y * gx + blockIdx.x;
  int swz = bid;
  if ((nwg & 7) == 0) swz = (bid & 7) * (nwg >> 3) + (bid >> 3);
  int mIdx, nIdx;
  if (CHUNK_M) { nIdx = swz % gx; mIdx = swz / gx; }
  else         { mIdx = swz % gy; nIdx = swz / gy; }
  const int m0 = mIdx * 128;
  const int n0 = nIdx * TN;

  const int q = lane & 15, G = lane >> 4;
  const int s7 = q & 7;
  const int srow = tid >> 3;
  const int scol = ((tid & 7) ^ (srow & 7)) << 3;

  f32x4 acc[4][NFR] = {};

  auto stage = [&](int buf, int kt) {
    const int k0 = kOff + (kt << 6);
    #pragma unroll
    for (int j = 0; j < 4; ++j) {
      gload_lds16(A + (size_t)(m0 + j*32 + srow) * Kstr + k0 + scol,
                  &As[buf][(j * 256 + wid * 64) << 3]);
    }
    #pragma unroll
    for (int j = 0; j < BCH; ++j) {
      gload_lds16(Bw + (size_t)(n0 + j*32 + srow) * Kstr + k0 + scol,
                  &Bs[buf][(j * 256 + wid * 64) << 3]);
    }
  };

  stage(0, 0);
  asm volatile("s_waitcnt vmcnt(0)" ::: "memory");
  __syncthreads();

  int cur = 0;
  for (int kt = 0; kt < nk; ++kt) {
    if (kt + 1 < nk) stage(cur ^ 1, kt + 1);
    #pragma unroll
    for (int kk = 0; kk < 2; ++kk) {
      const int c0 = kk * 4 + G;
      bf16x8 af[4], bfr[NFR];
      #pragma unroll
      for (int m = 0; m < 4; ++m)
        af[m] = *(const bf16x8*)(&As[cur][(wr*64 + m*16 + q) * 64 + ((c0 ^ s7) << 3)]);
      #pragma unroll
      for (int n = 0; n < NFR; ++n)
        bfr[n] = *(const bf16x8*)(&Bs[cur][(wc*(TN/2) + n*16 + q) * 64 + ((c0 ^ s7) << 3)]);
      #pragma unroll
      for (int m = 0; m < 4; ++m)
        #pragma unroll
        for (int n = 0; n < NFR; ++n)
          acc[m][n] = mfma16(af[m], bfr[n], acc[m][n]);
    }
    asm volatile("s_waitcnt vmcnt(0)" ::: "memory");
    __syncthreads();
    cur ^= 1;
  }

  const int rb = G << 2;
  const int cl = q;
  if (EPI == 2) {
    #pragma unroll
    for (int m = 0; m < 4; ++m) {
      #pragma unroll
      for (int np = 0; np < NFR/2; ++np) {
        int ca = n0 + wc*(TN/2) + (2*np)*16 + cl;
        int cg = ca + 16;
        float ba = bias[ca], bg = bias[cg];
        int colo = ((ca >> 5) << 4) + cl;
        #pragma unroll
        for (int r = 0; r < 4; ++r) {
          int row = m0 + wr*64 + m*16 + rb + r;
          float av = acc[m][2*np][r] + ba;
          float gv = acc[m][2*np+1][r] + bg;
          float gl = 0.5f * gv * (1.f + erff(gv * 0.70710678118654752f));
          ((bf16*)Cout)[(size_t)row * (N_ >> 1) + colo] = (bf16)(av * gl);
        }
      }
    }
  } else if (EPI == 3) {
    #pragma unroll
    for (int m = 0; m < 4; ++m) {
      #pragma unroll
      for (int n = 0; n < NFR; ++n) {
        int col = n0 + wc*(TN/2) + n*16 + cl;
        float bv = (z == 0) ? bias[col] : 0.f;
        #pragma unroll
        for (int r = 0; r < 4; ++r) {
          int row = m0 + wr*64 + m*16 + rb + r;
          atomicAdd((float*)Cout + (size_t)row * N_ + col, acc[m][n][r] + bv);
        }
      }
    }
  } else {
    #pragma unroll
    for (int m = 0; m < 4; ++m) {
      #pragma unroll
      for (int n = 0; n < NFR; ++n) {
        int col = n0 + wc*(TN/2) + n*16 + cl;
        float bv = bias[col];
        #pragma unroll
        for (int r = 0; r < 4; ++r) {
          int row = m0 + wr*64 + m*16 + rb + r;
          ((bf16*)Cout)[(size_t)row * N_ + col] = (bf16)(acc[m][n][r] + bv);
        }
      }
    }
  }
}

// ---------------- Flash attention, split-KV=2, swapped QK^T ----------------
// S = mfma(K, Q): lane holds 16 scores of ONE q-row (q=lane&15), keys
// k = nt*16 + G*4 + r. Softmax state (m,l) is per-lane scalar. P stays in
// registers: cvt_pk pairs + ds_bpermute assemble the PV A-fragment.
__global__ __launch_bounds__(256) void attn_kernel(const bf16* __restrict__ qkv,
    const float* __restrict__ slopes, float* __restrict__ Opart, float* __restrict__ ml) {
  const int tid = threadIdx.x, lane = tid & 63, wid = tid >> 6;
  const int bh = blockIdx.y;
  const int b = bh >> 4, h = bh & 15;
  const int kvz = blockIdx.z;
  const int kv0 = kvz * (LSEQ / NSPLIT);
  const float slope2 = slopes[h] * LOG2E;
  const float SC = 0.125f * LOG2E;
  const int qw = blockIdx.x * 64 + wid * 16;

  __shared__ __attribute__((aligned(16))) bf16     Kt[64 * 72];
  __shared__ __attribute__((aligned(16))) uint32_t V32[64 * 36];

  const size_t rs = 3 * DMODEL;
  const size_t base = (size_t)b * LSEQ * rs;
  const int q = lane & 15, G = lane >> 4;
  const float qi = (float)(qw + q);

  bf16x8 qf[2];
  {
    const bf16* p = qkv + base + (size_t)(qw + q) * rs + h * HDIM + (G << 3);
    qf[0] = *(const bf16x8*)p;
    qf[1] = *(const bf16x8*)(p + 32);
  }

  f32x4 accO[4] = {};
  float mreg = -1e30f, lreg = 0.f;

  const int trow = tid >> 2;
  const int tcol = (tid & 3) << 4;

  bf16x8 kreg0, kreg1, vreg0, vreg1;
  {
    const bf16* kp = qkv + base + (size_t)(kv0 + trow) * rs + DMODEL + h * HDIM + tcol;
    kreg0 = *(const bf16x8*)kp; kreg1 = *(const bf16x8*)(kp + 8);
    const bf16* vp = qkv + base + (size_t)(kv0 + trow) * rs + 2 * DMODEL + h * HDIM + tcol;
    vreg0 = *(const bf16x8*)vp; vreg1 = *(const bf16x8*)(vp + 8);
  }

  for (int kv = kv0; kv < kv0 + LSEQ / NSPLIT; kv += 64) {
    __syncthreads();
    *(bf16x8*)(Kt + trow * 72 + tcol)     = kreg0;
    *(bf16x8*)(Kt + trow * 72 + tcol + 8) = kreg1;
    {
      u32x4 va = __builtin_bit_cast(u32x4, vreg0);
      u32x4 vb = __builtin_bit_cast(u32x4, vreg1);
      u32x4 pa, pb;
      #pragma unroll
      for (int i = 0; i < 4; ++i) {
        pa[i] = (uint32_t)__shfl_xor((int)va[i], 4);
        pb[i] = (uint32_t)__shfl_xor((int)vb[i], 4);
      }
      const bool oddk = (trow & 1);
      const int d0 = tcol + (oddk ? 8 : 0);
      u32x4 m = oddk ? vb : va;
      u32x4 oo = oddk ? pb : pa;
      const int kpair = trow >> 1;
      const int swz = kpair ^ ((d0 >> 3) << 1);
      #pragma unroll
      for (int i = 0; i < 4; ++i) {
        uint32_t lo = oddk ? oo[i] : m[i];
        uint32_t hi = oddk ? m[i] : oo[i];
        uint32_t w0 = (lo & 0xffffu) | (hi << 16);
        uint32_t w1 = (lo >> 16) | (hi & 0xffff0000u);
        V32[(d0 + 2*i)     * 36 + swz] = w0;
        V32[(d0 + 2*i + 1) * 36 + swz] = w1;
      }
    }
    __syncthreads();

    if (kv + 64 < kv0 + LSEQ / NSPLIT) {
      const bf16* kp = qkv + base + (size_t)(kv + 64 + trow) * rs + DMODEL + h * HDIM + tcol;
      kreg0 = *(const bf16x8*)kp; kreg1 = *(const bf16x8*)(kp + 8);
      const bf16* vp = qkv + base + (size_t)(kv + 64 + trow) * rs + 2 * DMODEL + h * HDIM + tcol;
      vreg0 = *(const bf16x8*)vp; vreg1 = *(const bf16x8*)(vp + 8);
    }

    // ---- QK^T swapped: S[key][q], lane's regs = one q-row ----
    f32x4 sacc[4] = {};
    __builtin_amdgcn_s_setprio(1);
    #pragma unroll
    for (int nt = 0; nt < 4; ++nt) {
      const bf16* kb = Kt + (nt * 16 + q) * 72 + (G << 3);
      sacc[nt] = mfma16(*(const bf16x8*)kb, qf[0], sacc[nt]);
      sacc[nt] = mfma16(*(const bf16x8*)(kb + 32), qf[1], sacc[nt]);
    }
    __builtin_amdgcn_s_setprio(0);

    // ---- bias + row max (in-register + 2 shfl) ----
    float pv[4][4];
    float pmax = -1e30f;
    #pragma unroll
    for (int nt = 0; nt < 4; ++nt) {
      #pragma unroll
      for (int r = 0; r < 4; ++r) {
        float kj = (float)(kv + nt * 16 + (G << 2) + r);
        float s = sacc[nt][r] * SC - slope2 * fabsf(qi - kj);
        pv[nt][r] = s;
        pmax = fmaxf(pmax, s);
      }
    }
    pmax = fmaxf(pmax, __shfl_xor(pmax, 16));
    pmax = fmaxf(pmax, __shfl_xor(pmax, 32));

    // ---- defer-max (T13): rescale only when max grew past threshold ----
    if (!__all(pmax <= mreg + 8.f)) {
      float mnew = fmaxf(mreg, pmax);
      float ef = exp2f(mreg - mnew);
      mreg = mnew;
      lreg *= ef;
      float efr[4];
      #pragma unroll
      for (int r = 0; r < 4; ++r)
        efr[r] = __shfl(ef, (G << 4) + (G << 2) + r);
      #pragma unroll
      for (int dn = 0; dn < 4; ++dn)
        #pragma unroll
        for (int r = 0; r < 4; ++r)
          accO[dn][r] *= efr[r];
    }

    // ---- P = exp2(s - m), row sum ----
    float rsum = 0.f;
    #pragma unroll
    for (int nt = 0; nt < 4; ++nt) {
      #pragma unroll
      for (int r = 0; r < 4; ++r) {
        float pe = exp2f(pv[nt][r] - mreg);
        pv[nt][r] = pe;
        rsum += pe;
      }
    }
    rsum += __shfl_xor(rsum, 16);
    rsum += __shfl_xor(rsum, 32);
    lreg += rsum;

    // ---- pack P pairs to bf16 (keys nt*16+4G+{2s,2s+1} in wp[nt][s]) ----
    uint32_t wp[4][2];
    #pragma unroll
    for (int nt = 0; nt < 4; ++nt) {
      asm("v_cvt_pk_bf16_f32 %0, %1, %2" : "=v"(wp[nt][0]) : "v"(pv[nt][0]), "v"(pv[nt][1]));
      asm("v_cvt_pk_bf16_f32 %0, %1, %2" : "=v"(wp[nt][1]) : "v"(pv[nt][2]), "v"(pv[nt][3]));
    }

    // ---- PV: assemble A-frag via bpermute, V from LDS ----
    __builtin_amdgcn_s_setprio(1);
    #pragma unroll
    for (int chunk = 0; chunk < 2; ++chunk) {
      u32x4 u;
      #pragma unroll
      for (int j = 0; j < 4; ++j) {
        int src = (((G & 1) * 2 + (j >> 1)) << 4) | q;
        uint32_t lo2 = (uint32_t)__shfl((int)wp[2*chunk][j & 1], src);
        uint32_t hi2 = (uint32_t)__shfl((int)wp[2*chunk + 1][j & 1], src);
        u[j] = (G & 2) ? hi2 : lo2;
      }
      bf16x8 pf = __builtin_bit_cast(bf16x8, u);
      #pragma unroll
      for (int dn = 0; dn < 4; ++dn) {
        const int d = dn * 16 + q;
        u32x4 raw = *(const u32x4*)(V32 + d * 36 + chunk * 16 + 4 * (G ^ dn));
        if ((lane >> 3) & 1) raw = __builtin_shufflevector(raw, raw, 2, 3, 0, 1);
        bf16x8 vf = __builtin_bit_cast(bf16x8, raw);
        accO[dn] = mfma16(pf, vf, accO[dn]);
      }
    }
    __builtin_amdgcn_s_setprio(0);
  }

  #pragma unroll
  for (int r = 0; r < 4; ++r) {
    int qr = qw + (G << 2) + r;
    size_t obase = ((size_t)(kvz * 32 + bh) * LSEQ + qr) * HDIM;
    #pragma unroll
    for (int dn = 0; dn < 4; ++dn)
      Opart[obase + dn * 16 + q] = accO[dn][r];
  }
  if (lane < 16) {
    size_t mb = ((size_t)(kvz * 32 + bh) * LSEQ + qw + lane) * 2;
    ml[mb]     = mreg;
    ml[mb + 1] = lreg;
  }
}

// combine NSPLIT kv-parts
__global__ __launch_bounds__(256) void attn_combine(const float* __restrict__ Opart,
    const float* __restrict__ ml, bf16* __restrict__ o) {
  int idx = blockIdx.x * 256 + threadIdx.x;
  int bh = idx >> 14;
  int rem = idx & 16383;
  int qr = rem >> 4;
  int d4 = (rem & 15) << 2;
  float mz[NSPLIT], lz[NSPLIT];
  float m = -1e30f;
  #pragma unroll
  for (int z = 0; z < NSPLIT; ++z) {
    size_t rz = ((size_t)(z * 32 + bh) * LSEQ + qr) * 2;
    mz[z] = ml[rz]; lz[z] = ml[rz + 1];
    m = fmaxf(m, mz[z]);
  }
  float wz[NSPLIT];
  float l = 0.f;
  #pragma unroll
  for (int z = 0; z < NSPLIT; ++z) { wz[z] = exp2f(mz[z] - m); l += lz[z] * wz[z]; }
  float inv = 1.f / l;
  float ax = 0, ay = 0, az = 0, aw = 0;
  #pragma unroll
  for (int z = 0; z < NSPLIT; ++z) {
    size_t rz = (size_t)(z * 32 + bh) * LSEQ + qr;
    float4 ov = *(const float4*)(Opart + rz * HDIM + d4);
    ax += ov.x * wz[z]; ay += ov.y * wz[z]; az += ov.z * wz[z]; aw += ov.w * wz[z];
  }
  int b = bh >> 4, h = bh & 15;
  bf16* op = o + ((size_t)(b * LSEQ + qr) * DMODEL + h * HDIM + d4);
  op[0] = (bf16)(ax * inv);
  op[1] = (bf16)(ay * inv);
  op[2] = (bf16)(az * inv);
  op[3] = (bf16)(aw * inv);
}

// ---------------- host ----------------
extern "C" void kernel_launch(void* const* d_in, const int* in_sizes, int n_in,
                              void* d_out, int out_size, void* d_ws, size_t ws_size,
                              hipStream_t stream) {
  const float* x_in      = (const float*)d_in[0];
  const float* slopes    = (const float*)d_in[1];
  const float* g_attn    = (const float*)d_in[2];
  const float* w_in      = (const float*)d_in[3];
  const float* b_in      = (const float*)d_in[4];
  const float* w_out     = (const float*)d_in[5];
  const float* b_out     = (const float*)d_in[6];
  const float* g_ff      = (const float*)d_in[7];
  const float* w1        = (const float*)d_in[8];
  const float* b1        = (const float*)d_in[9];
  const float* w2        = (const float*)d_in[10];
  const float* b2        = (const float*)d_in[11];
  const float* g_final   = (const float*)d_in[12];

  char* p = (char*)d_ws;
  float* xw   = (float*)p;              p += (size_t)MROWS * DMODEL * 4;
  bf16* abuf  = (bf16*)p;               p += (size_t)MROWS * DMODEL * 2;
  bf16* qkvb  = (bf16*)p;               p += (size_t)MROWS * 3 * DMODEL * 2;
  bf16* obuf  = (bf16*)p;               p += (size_t)MROWS * DMODEL * 2;
  bf16* gbuf  = (bf16*)p;               p += (size_t)MROWS * INNERP * 2;
  float* Opart = (float*)p;             p += (size_t)NSPLIT * 32 * LSEQ * HDIM * 4;
  float* mlb   = (float*)p;             p += (size_t)NSPLIT * 32 * LSEQ * 2 * 4;
  bf16* w_in_b  = (bf16*)p;             p += (size_t)DEPTH * 3 * DMODEL * DMODEL * 2;
  bf16* w_out_b = (bf16*)p;             p += (size_t)DEPTH * DMODEL * DMODEL * 2;
  bf16* w1p     = (bf16*)p;             p += (size_t)DEPTH * N1P * DMODEL * 2;
  bf16* w2p     = (bf16*)p;             p += (size_t)DEPTH * DMODEL * INNERP * 2;
  float* b1p    = (float*)p;            p += (size_t)DEPTH * N1P * 4;

  hipMemcpyAsync(xw, x_in, (size_t)MROWS * DMODEL * 4, hipMemcpyDeviceToDevice, stream);

  conv_bf16_kernel<<<6144, 256, 0, stream>>>(w_in, w_in_b, (size_t)DEPTH * 3 * DMODEL * DMODEL);
  conv_bf16_kernel<<<2048, 256, 0, stream>>>(w_out, w_out_b, (size_t)DEPTH * DMODEL * DMODEL);
  conv_w1_kernel<<<11008, 256, 0, stream>>>(w1, w1p);
  conv_b1_kernel<<<86, 256, 0, stream>>>(b1, b1p);
  conv_w2_kernel<<<5504, 256, 0, stream>>>(w2, w2p);

  for (int i = 0; i < DEPTH; ++i) {
    rmsnorm_kernel<true><<<MROWS, 256, 0, stream>>>(xw, g_attn + i * DMODEL, abuf);
    // qkv: (M,N,K) = (2048, 3072, 1024), bf16 out
    gemm_bt<64, 0, false><<<dim3(48, 16), 256, 0, stream>>>(
        abuf, w_in_b + (size_t)i * 3 * DMODEL * DMODEL, b_in + i * 3 * DMODEL,
        qkvb, MROWS, 3 * DMODEL, DMODEL, 16, 16);
    attn_kernel<<<dim3(16, 32, NSPLIT), 256, 0, stream>>>(qkvb, slopes, Opart, mlb);
    attn_combine<<<2048, 256, 0, stream>>>(Opart, mlb, obuf);
    // out-proj: (2048, 1024, 1024), split-K=2, atomic into xw (residual)
    gemm_bt<64, 3, true><<<dim3(16, 16, 2), 256, 0, stream>>>(
        obuf, w_out_b + (size_t)i * DMODEL * DMODEL, b_out + i * DMODEL,
        xw, MROWS, DMODEL, DMODEL, 8, 16);
    rmsnorm_kernel<true><<<MROWS, 256, 0, stream>>>(xw, g_ff + i * DMODEL, abuf);
    // w1 + GEGLU: (2048, 5504, 1024) -> gbuf (2048 x 2752 bf16)
    gemm_bt<64, 2, false><<<dim3(86, 16), 256, 0, stream>>>(
        abuf, w1p + (size_t)i * N1P * DMODEL, b1p + i * N1P,
        gbuf, MROWS, N1P, DMODEL, 16, 16);
    // w2: (2048, 1024, 2752), split-K=2 (22+21 steps), atomic into xw
    gemm_bt<64, 3, true><<<dim3(16, 16, 2), 256, 0, stream>>>(
        gbuf, w2p + (size_t)i * DMODEL * INNERP, b2 + i * DMODEL,
        xw, MROWS, DMODEL, INNERP, 22, 43);
  }
  rmsnorm_kernel<false><<<MROWS, 256, 0, stream>>>(xw, g_final, d_out);
}

// Round 9
// 699.034 us; speedup vs baseline: 1.3166x; 1.0028x over previous
//
#include <hip/hip_runtime.h>

#define DEPTH   4
#define BSZ     2
#define LSEQ    1024
#define DMODEL  1024
#define NHEAD   16
#define HDIM    64
#define MROWS   (BSZ*LSEQ)    // 2048
#define INNER   2730
#define INNERP  2752
#define N1      (2*INNER)     // 5460
#define N1P     (2*INNERP)    // 5504
#define LOG2E   1.4426950408889634f
#define NSPLIT  2

typedef __bf16 bf16;
typedef bf16  bf16x8 __attribute__((ext_vector_type(8)));
typedef float f32x4  __attribute__((ext_vector_type(4)));
typedef uint32_t u32x4 __attribute__((ext_vector_type(4)));

__device__ inline f32x4 mfma16(bf16x8 a, bf16x8 b, f32x4 c) {
  return __builtin_amdgcn_mfma_f32_16x16x32_bf16(a, b, c, 0, 0, 0);
}

__device__ inline void gload_lds16(const void* g, void* l) {
  __builtin_amdgcn_global_load_lds(
      (const __attribute__((address_space(1))) void*)g,
      (__attribute__((address_space(3))) void*)l, 16, 0, 0);
}

// ---------------- weight conversion (vectorized stores) ----------------
__global__ void conv_bf16_kernel(const float* __restrict__ src, bf16* __restrict__ dst, size_t n) {
  size_t i = ((size_t)blockIdx.x * 256 + threadIdx.x) * 8;
  if (i >= n) return;
  float4 v0 = *(const float4*)(src + i);
  float4 v1 = *(const float4*)(src + i + 4);
  bf16x8 o = { (bf16)v0.x,(bf16)v0.y,(bf16)v0.z,(bf16)v0.w,
               (bf16)v1.x,(bf16)v1.y,(bf16)v1.z,(bf16)v1.w };
  *(bf16x8*)(dst + i) = o;
}

// ff_w1 (DEPTH,5460,1024) -> padded interleaved (DEPTH,5504,1024):
// padded row rp: p=rp>>4, w=rp&15, col=(p>>1)*16+w; even p -> a-row col,
// odd p -> gate-row INNER+col; col>=INNER -> zero.
__global__ void conv_w1_kernel(const float* __restrict__ src, bf16* __restrict__ dst) {
  size_t i = ((size_t)blockIdx.x * 256 + threadIdx.x) * 8;
  const size_t tot = (size_t)DEPTH * N1P * DMODEL;
  if (i >= tot) return;
  int d  = (int)(i / ((size_t)N1P * DMODEL));
  int rem = (int)(i % ((size_t)N1P * DMODEL));
  int rp = rem / DMODEL, k = rem % DMODEL;
  int p2 = rp >> 4, w = rp & 15;
  int col = ((p2 >> 1) << 4) + w;
  bf16x8 o;
  if (col >= INNER) {
    o = (bf16x8)(bf16)0.f;
  } else {
    int rs = (p2 & 1) ? (INNER + col) : col;
    const float* s = src + ((size_t)d * N1 + rs) * DMODEL + k;
    float4 v0 = *(const float4*)s;
    float4 v1 = *(const float4*)(s + 4);
    o = bf16x8{ (bf16)v0.x,(bf16)v0.y,(bf16)v0.z,(bf16)v0.w,
                (bf16)v1.x,(bf16)v1.y,(bf16)v1.z,(bf16)v1.w };
  }
  *(bf16x8*)(dst + i) = o;
}

__global__ void conv_b1_kernel(const float* __restrict__ src, float* __restrict__ dst) {
  int i = blockIdx.x * 256 + threadIdx.x;
  if (i >= DEPTH * N1P) return;
  int d = i / N1P, rp = i % N1P;
  int p2 = rp >> 4, w = rp & 15;
  int col = ((p2 >> 1) << 4) + w;
  float v = 0.f;
  if (col < INNER) v = src[d * N1 + ((p2 & 1) ? (INNER + col) : col)];
  dst[i] = v;
}

__global__ void conv_w2_kernel(const float* __restrict__ src, bf16* __restrict__ dst) {
  size_t i = ((size_t)blockIdx.x * 256 + threadIdx.x) * 8;
  const size_t tot = (size_t)DEPTH * DMODEL * INNERP;
  if (i >= tot) return;
  size_t dn = i / INNERP;
  int kp = (int)(i % INNERP);
  const float* s = src + dn * INNER;
  bf16x8 o;
  #pragma unroll
  for (int j = 0; j < 8; ++j) {
    int k = kp + j;
    o[j] = (k < INNER) ? (bf16)s[k] : (bf16)0.f;
  }
  *(bf16x8*)(dst + i) = o;
}

// ---------------- RMSNorm ----------------
template<bool OUT_BF16>
__global__ __launch_bounds__(256) void rmsnorm_kernel(const float* __restrict__ x,
    const float* __restrict__ gamma, void* __restrict__ out) {
  const int row = blockIdx.x;
  const int tid = threadIdx.x;
  const float4 v = *(const float4*)(x + (size_t)row * DMODEL + tid * 4);
  float ss = v.x*v.x + v.y*v.y + v.z*v.z + v.w*v.w;
  for (int m = 1; m < 64; m <<= 1) ss += __shfl_xor(ss, m);
  __shared__ float ws4[4];
  if ((tid & 63) == 0) ws4[tid >> 6] = ss;
  __syncthreads();
  float tot = ws4[0] + ws4[1] + ws4[2] + ws4[3];
  float scale = 32.0f / fmaxf(sqrtf(tot), 1e-12f);
  const float4 g = *(const float4*)(gamma + tid * 4);
  float o0 = v.x*scale*g.x, o1 = v.y*scale*g.y, o2 = v.z*scale*g.z, o3 = v.w*scale*g.w;
  size_t p = (size_t)row * DMODEL + tid * 4;
  if (OUT_BF16) {
    bf16* ob = (bf16*)out;
    ob[p+0] = (bf16)o0; ob[p+1] = (bf16)o1; ob[p+2] = (bf16)o2; ob[p+3] = (bf16)o3;
  } else {
    *(float4*)((float*)out + p) = make_float4(o0, o1, o2, o3);
  }
}

// ---------------- GEMM: C(MxN) = A(MxK) @ W(NxK)^T ----------------
// 2-deep pipelined staging with counted vmcnt (T4): both LDS buffers staged
// ahead; per K-step wait only the OLDER stage batch (vmcnt(6)), raw s_barrier
// (compiler-fenced with "memory" asm), compute, lgkmcnt(0)+barrier, refill
// freed buffer for t+2. Loads for step t issued at t-2.
// EPI: 0 = bf16 out + bias; 2 = fused GEGLU + bias; 3 = f32 atomicAdd
// partial into Cout (residual accumulator), bias added by z==0 only.
template<int TN, int EPI, bool CHUNK_M>
__global__ __launch_bounds__(256) void gemm_bt(const bf16* __restrict__ A,
    const bf16* __restrict__ Bw, const float* __restrict__ bias,
    void* __restrict__ Cout, int M_, int N_, int Kstr, int nk0, int nkTot) {
  constexpr int NFR = TN / 32;
  constexpr int BCH = TN / 32;
  __shared__ __attribute__((aligned(16))) bf16 As[2][128 * 64];
  __shared__ __attribute__((aligned(16))) bf16 Bs[2][TN * 64];
  const int tid  = threadIdx.x;
  const int lane = tid & 63;
  const int wid  = tid >> 6;
  const int wr = wid >> 1, wc = wid & 1;

  const int z = blockIdx.z;
  const int nk  = z ? (nkTot - nk0) : nk0;
  const int kOff = z * (nk0 << 6);

  const int gx = gridDim.x, gy = gridDim.y;
  const int nwg = gx * gy;
  int bid = blockIdx.y * gx + blockIdx.x;
  int swz = bid;
  if ((nwg & 7) == 0) swz = (bid & 7) * (nwg >> 3) + (bid >> 3);
  int mIdx, nIdx;
  if (CHUNK_M) { nIdx = swz % gx; mIdx = swz / gx; }
  else         { mIdx = swz % gy; nIdx = swz / gy; }
  const int m0 = mIdx * 128;
  const int n0 = nIdx * TN;

  const int q = lane & 15, G = lane >> 4;
  const int s7 = q & 7;
  const int srow = tid >> 3;
  const int scol = ((tid & 7) ^ (srow & 7)) << 3;

  f32x4 acc[4][NFR] = {};

  auto stage = [&](int buf, int kt) {
    const int k0 = kOff + (kt << 6);
    #pragma unroll
    for (int j = 0; j < 4; ++j) {
      gload_lds16(A + (size_t)(m0 + j*32 + srow) * Kstr + k0 + scol,
                  &As[buf][(j * 256 + wid * 64) << 3]);
    }
    #pragma unroll
    for (int j = 0; j < BCH; ++j) {
      gload_lds16(Bw + (size_t)(n0 + j*32 + srow) * Kstr + k0 + scol,
                  &Bs[buf][(j * 256 + wid * 64) << 3]);
    }
  };

  stage(0, 0);
  if (nk > 1) stage(1, 1);

  int cur = 0;
  for (int kt = 0; kt < nk; ++kt) {
    // wait own loads for buf[cur] (older batch); keep newer batch in flight
    if (kt < nk - 1) {
      if constexpr (TN == 64) asm volatile("s_waitcnt vmcnt(6)" ::: "memory");
      else                    asm volatile("s_waitcnt vmcnt(8)" ::: "memory");
    } else {
      asm volatile("s_waitcnt vmcnt(0)" ::: "memory");
    }
    __builtin_amdgcn_s_barrier();          // all waves' DMA landed -> buffer valid
    asm volatile("" ::: "memory");         // fence: no LDS read hoists above barrier

    #pragma unroll
    for (int kk = 0; kk < 2; ++kk) {
      const int c0 = kk * 4 + G;
      bf16x8 af[4], bfr[NFR];
      #pragma unroll
      for (int m = 0; m < 4; ++m)
        af[m] = *(const bf16x8*)(&As[cur][(wr*64 + m*16 + q) * 64 + ((c0 ^ s7) << 3)]);
      #pragma unroll
      for (int n = 0; n < NFR; ++n)
        bfr[n] = *(const bf16x8*)(&Bs[cur][(wc*(TN/2) + n*16 + q) * 64 + ((c0 ^ s7) << 3)]);
      #pragma unroll
      for (int m = 0; m < 4; ++m)
        #pragma unroll
        for (int n = 0; n < NFR; ++n)
          acc[m][n] = mfma16(af[m], bfr[n], acc[m][n]);
    }

    asm volatile("s_waitcnt lgkmcnt(0)" ::: "memory");  // own LDS reads retired
    __builtin_amdgcn_s_barrier();          // all waves done reading buf[cur]
    asm volatile("" ::: "memory");         // fence: no DMA issue hoists above
    if (kt + 2 < nk) stage(cur, kt + 2);   // refill freed buffer
    cur ^= 1;
  }

  const int rb = G << 2;
  const int cl = q;
  if (EPI == 2) {
    #pragma unroll
    for (int m = 0; m < 4; ++m) {
      #pragma unroll
      for (int np = 0; np < NFR/2; ++np) {
        int ca = n0 + wc*(TN/2) + (2*np)*16 + cl;
        int cg = ca + 16;
        float ba = bias[ca], bg = bias[cg];
        int colo = ((ca >> 5) << 4) + cl;
        #pragma unroll
        for (int r = 0; r < 4; ++r) {
          int row = m0 + wr*64 + m*16 + rb + r;
          float av = acc[m][2*np][r] + ba;
          float gv = acc[m][2*np+1][r] + bg;
          float gl = 0.5f * gv * (1.f + erff(gv * 0.70710678118654752f));
          ((bf16*)Cout)[(size_t)row * (N_ >> 1) + colo] = (bf16)(av * gl);
        }
      }
    }
  } else if (EPI == 3) {
    #pragma unroll
    for (int m = 0; m < 4; ++m) {
      #pragma unroll
      for (int n = 0; n < NFR; ++n) {
        int col = n0 + wc*(TN/2) + n*16 + cl;
        float bv = (z == 0) ? bias[col] : 0.f;
        #pragma unroll
        for (int r = 0; r < 4; ++r) {
          int row = m0 + wr*64 + m*16 + rb + r;
          atomicAdd((float*)Cout + (size_t)row * N_ + col, acc[m][n][r] + bv);
        }
      }
    }
  } else {
    #pragma unroll
    for (int m = 0; m < 4; ++m) {
      #pragma unroll
      for (int n = 0; n < NFR; ++n) {
        int col = n0 + wc*(TN/2) + n*16 + cl;
        float bv = bias[col];
        #pragma unroll
        for (int r = 0; r < 4; ++r) {
          int row = m0 + wr*64 + m*16 + rb + r;
          ((bf16*)Cout)[(size_t)row * N_ + col] = (bf16)(acc[m][n][r] + bv);
        }
      }
    }
  }
}

// ---------------- Flash attention, split-KV=2, swapped QK^T ----------------
// S = mfma(K, Q): lane holds 16 scores of ONE q-row (q=lane&15), keys
// k = nt*16 + G*4 + r. Softmax state (m,l) is per-lane scalar. P stays in
// registers: cvt_pk pairs + shfl assemble the PV A-fragment.
__global__ __launch_bounds__(256) void attn_kernel(const bf16* __restrict__ qkv,
    const float* __restrict__ slopes, float* __restrict__ Opart, float* __restrict__ ml) {
  const int tid = threadIdx.x, lane = tid & 63, wid = tid >> 6;
  const int bh = blockIdx.y;
  const int b = bh >> 4, h = bh & 15;
  const int kvz = blockIdx.z;
  const int kv0 = kvz * (LSEQ / NSPLIT);
  const float slope2 = slopes[h] * LOG2E;
  const float SC = 0.125f * LOG2E;
  const int qw = blockIdx.x * 64 + wid * 16;

  __shared__ __attribute__((aligned(16))) bf16     Kt[64 * 72];
  __shared__ __attribute__((aligned(16))) uint32_t V32[64 * 36];

  const size_t rs = 3 * DMODEL;
  const size_t base = (size_t)b * LSEQ * rs;
  const int q = lane & 15, G = lane >> 4;
  const float qi = (float)(qw + q);

  bf16x8 qf[2];
  {
    const bf16* p = qkv + base + (size_t)(qw + q) * rs + h * HDIM + (G << 3);
    qf[0] = *(const bf16x8*)p;
    qf[1] = *(const bf16x8*)(p + 32);
  }

  f32x4 accO[4] = {};
  float mreg = -1e30f, lreg = 0.f;

  const int trow = tid >> 2;
  const int tcol = (tid & 3) << 4;

  bf16x8 kreg0, kreg1, vreg0, vreg1;
  {
    const bf16* kp = qkv + base + (size_t)(kv0 + trow) * rs + DMODEL + h * HDIM + tcol;
    kreg0 = *(const bf16x8*)kp; kreg1 = *(const bf16x8*)(kp + 8);
    const bf16* vp = qkv + base + (size_t)(kv0 + trow) * rs + 2 * DMODEL + h * HDIM + tcol;
    vreg0 = *(const bf16x8*)vp; vreg1 = *(const bf16x8*)(vp + 8);
  }

  for (int kv = kv0; kv < kv0 + LSEQ / NSPLIT; kv += 64) {
    __syncthreads();
    *(bf16x8*)(Kt + trow * 72 + tcol)     = kreg0;
    *(bf16x8*)(Kt + trow * 72 + tcol + 8) = kreg1;
    {
      u32x4 va = __builtin_bit_cast(u32x4, vreg0);
      u32x4 vb = __builtin_bit_cast(u32x4, vreg1);
      u32x4 pa, pb;
      #pragma unroll
      for (int i = 0; i < 4; ++i) {
        pa[i] = (uint32_t)__shfl_xor((int)va[i], 4);
        pb[i] = (uint32_t)__shfl_xor((int)vb[i], 4);
      }
      const bool oddk = (trow & 1);
      const int d0 = tcol + (oddk ? 8 : 0);
      u32x4 m = oddk ? vb : va;
      u32x4 oo = oddk ? pb : pa;
      const int kpair = trow >> 1;
      const int swz = kpair ^ ((d0 >> 3) << 1);
      #pragma unroll
      for (int i = 0; i < 4; ++i) {
        uint32_t lo = oddk ? oo[i] : m[i];
        uint32_t hi = oddk ? m[i] : oo[i];
        uint32_t w0 = (lo & 0xffffu) | (hi << 16);
        uint32_t w1 = (lo >> 16) | (hi & 0xffff0000u);
        V32[(d0 + 2*i)     * 36 + swz] = w0;
        V32[(d0 + 2*i + 1) * 36 + swz] = w1;
      }
    }
    __syncthreads();

    if (kv + 64 < kv0 + LSEQ / NSPLIT) {
      const bf16* kp = qkv + base + (size_t)(kv + 64 + trow) * rs + DMODEL + h * HDIM + tcol;
      kreg0 = *(const bf16x8*)kp; kreg1 = *(const bf16x8*)(kp + 8);
      const bf16* vp = qkv + base + (size_t)(kv + 64 + trow) * rs + 2 * DMODEL + h * HDIM + tcol;
      vreg0 = *(const bf16x8*)vp; vreg1 = *(const bf16x8*)(vp + 8);
    }

    // ---- QK^T swapped: S[key][q], lane's regs = one q-row ----
    f32x4 sacc[4] = {};
    __builtin_amdgcn_s_setprio(1);
    #pragma unroll
    for (int nt = 0; nt < 4; ++nt) {
      const bf16* kb = Kt + (nt * 16 + q) * 72 + (G << 3);
      sacc[nt] = mfma16(*(const bf16x8*)kb, qf[0], sacc[nt]);
      sacc[nt] = mfma16(*(const bf16x8*)(kb + 32), qf[1], sacc[nt]);
    }
    __builtin_amdgcn_s_setprio(0);

    // ---- bias + row max (in-register + 2 shfl) ----
    float pv[4][4];
    float pmax = -1e30f;
    #pragma unroll
    for (int nt = 0; nt < 4; ++nt) {
      #pragma unroll
      for (int r = 0; r < 4; ++r) {
        float kj = (float)(kv + nt * 16 + (G << 2) + r);
        float s = sacc[nt][r] * SC - slope2 * fabsf(qi - kj);
        pv[nt][r] = s;
        pmax = fmaxf(pmax, s);
      }
    }
    pmax = fmaxf(pmax, __shfl_xor(pmax, 16));
    pmax = fmaxf(pmax, __shfl_xor(pmax, 32));

    // ---- defer-max (T13): rescale only when max grew past threshold ----
    if (!__all(pmax <= mreg + 8.f)) {
      float mnew = fmaxf(mreg, pmax);
      float ef = exp2f(mreg - mnew);
      mreg = mnew;
      lreg *= ef;
      float efr[4];
      #pragma unroll
      for (int r = 0; r < 4; ++r)
        efr[r] = __shfl(ef, (G << 4) + (G << 2) + r);
      #pragma unroll
      for (int dn = 0; dn < 4; ++dn)
        #pragma unroll
        for (int r = 0; r < 4; ++r)
          accO[dn][r] *= efr[r];
    }

    // ---- P = exp2(s - m), row sum ----
    float rsum = 0.f;
    #pragma unroll
    for (int nt = 0; nt < 4; ++nt) {
      #pragma unroll
      for (int r = 0; r < 4; ++r) {
        float pe = exp2f(pv[nt][r] - mreg);
        pv[nt][r] = pe;
        rsum += pe;
      }
    }
    rsum += __shfl_xor(rsum, 16);
    rsum += __shfl_xor(rsum, 32);
    lreg += rsum;

    // ---- pack P pairs to bf16 (keys nt*16+4G+{2s,2s+1} in wp[nt][s]) ----
    uint32_t wp[4][2];
    #pragma unroll
    for (int nt = 0; nt < 4; ++nt) {
      asm("v_cvt_pk_bf16_f32 %0, %1, %2" : "=v"(wp[nt][0]) : "v"(pv[nt][0]), "v"(pv[nt][1]));
      asm("v_cvt_pk_bf16_f32 %0, %1, %2" : "=v"(wp[nt][1]) : "v"(pv[nt][2]), "v"(pv[nt][3]));
    }

    // ---- PV: assemble A-frag via shfl, V from LDS ----
    __builtin_amdgcn_s_setprio(1);
    #pragma unroll
    for (int chunk = 0; chunk < 2; ++chunk) {
      u32x4 u;
      #pragma unroll
      for (int j = 0; j < 4; ++j) {
        int src = (((G & 1) * 2 + (j >> 1)) << 4) | q;
        uint32_t lo2 = (uint32_t)__shfl((int)wp[2*chunk][j & 1], src);
        uint32_t hi2 = (uint32_t)__shfl((int)wp[2*chunk + 1][j & 1], src);
        u[j] = (G & 2) ? hi2 : lo2;
      }
      bf16x8 pf = __builtin_bit_cast(bf16x8, u);
      #pragma unroll
      for (int dn = 0; dn < 4; ++dn) {
        const int d = dn * 16 + q;
        u32x4 raw = *(const u32x4*)(V32 + d * 36 + chunk * 16 + 4 * (G ^ dn));
        if ((lane >> 3) & 1) raw = __builtin_shufflevector(raw, raw, 2, 3, 0, 1);
        bf16x8 vf = __builtin_bit_cast(bf16x8, raw);
        accO[dn] = mfma16(pf, vf, accO[dn]);
      }
    }
    __builtin_amdgcn_s_setprio(0);
  }

  #pragma unroll
  for (int r = 0; r < 4; ++r) {
    int qr = qw + (G << 2) + r;
    size_t obase = ((size_t)(kvz * 32 + bh) * LSEQ + qr) * HDIM;
    #pragma unroll
    for (int dn = 0; dn < 4; ++dn)
      Opart[obase + dn * 16 + q] = accO[dn][r];
  }
  if (lane < 16) {
    size_t mb = ((size_t)(kvz * 32 + bh) * LSEQ + qw + lane) * 2;
    ml[mb]     = mreg;
    ml[mb + 1] = lreg;
  }
}

// combine NSPLIT kv-parts
__global__ __launch_bounds__(256) void attn_combine(const float* __restrict__ Opart,
    const float* __restrict__ ml, bf16* __restrict__ o) {
  int idx = blockIdx.x * 256 + threadIdx.x;
  int bh = idx >> 14;
  int rem = idx & 16383;
  int qr = rem >> 4;
  int d4 = (rem & 15) << 2;
  float mz[NSPLIT], lz[NSPLIT];
  float m = -1e30f;
  #pragma unroll
  for (int z = 0; z < NSPLIT; ++z) {
    size_t rz = ((size_t)(z * 32 + bh) * LSEQ + qr) * 2;
    mz[z] = ml[rz]; lz[z] = ml[rz + 1];
    m = fmaxf(m, mz[z]);
  }
  float wz[NSPLIT];
  float l = 0.f;
  #pragma unroll
  for (int z = 0; z < NSPLIT; ++z) { wz[z] = exp2f(mz[z] - m); l += lz[z] * wz[z]; }
  float inv = 1.f / l;
  float ax = 0, ay = 0, az = 0, aw = 0;
  #pragma unroll
  for (int z = 0; z < NSPLIT; ++z) {
    size_t rz = (size_t)(z * 32 + bh) * LSEQ + qr;
    float4 ov = *(const float4*)(Opart + rz * HDIM + d4);
    ax += ov.x * wz[z]; ay += ov.y * wz[z]; az += ov.z * wz[z]; aw += ov.w * wz[z];
  }
  int b = bh >> 4, h = bh & 15;
  bf16* op = o + ((size_t)(b * LSEQ + qr) * DMODEL + h * HDIM + d4);
  op[0] = (bf16)(ax * inv);
  op[1] = (bf16)(ay * inv);
  op[2] = (bf16)(az * inv);
  op[3] = (bf16)(aw * inv);
}

// ---------------- host ----------------
extern "C" void kernel_launch(void* const* d_in, const int* in_sizes, int n_in,
                              void* d_out, int out_size, void* d_ws, size_t ws_size,
                              hipStream_t stream) {
  const float* x_in      = (const float*)d_in[0];
  const float* slopes    = (const float*)d_in[1];
  const float* g_attn    = (const float*)d_in[2];
  const float* w_in      = (const float*)d_in[3];
  const float* b_in      = (const float*)d_in[4];
  const float* w_out     = (const float*)d_in[5];
  const float* b_out     = (const float*)d_in[6];
  const float* g_ff      = (const float*)d_in[7];
  const float* w1        = (const float*)d_in[8];
  const float* b1        = (const float*)d_in[9];
  const float* w2        = (const float*)d_in[10];
  const float* b2        = (const float*)d_in[11];
  const float* g_final   = (const float*)d_in[12];

  char* p = (char*)d_ws;
  float* xw   = (float*)p;              p += (size_t)MROWS * DMODEL * 4;
  bf16* abuf  = (bf16*)p;               p += (size_t)MROWS * DMODEL * 2;
  bf16* qkvb  = (bf16*)p;               p += (size_t)MROWS * 3 * DMODEL * 2;
  bf16* obuf  = (bf16*)p;               p += (size_t)MROWS * DMODEL * 2;
  bf16* gbuf  = (bf16*)p;               p += (size_t)MROWS * INNERP * 2;
  float* Opart = (float*)p;             p += (size_t)NSPLIT * 32 * LSEQ * HDIM * 4;
  float* mlb   = (float*)p;             p += (size_t)NSPLIT * 32 * LSEQ * 2 * 4;
  bf16* w_in_b  = (bf16*)p;             p += (size_t)DEPTH * 3 * DMODEL * DMODEL * 2;
  bf16* w_out_b = (bf16*)p;             p += (size_t)DEPTH * DMODEL * DMODEL * 2;
  bf16* w1p     = (bf16*)p;             p += (size_t)DEPTH * N1P * DMODEL * 2;
  bf16* w2p     = (bf16*)p;             p += (size_t)DEPTH * DMODEL * INNERP * 2;
  float* b1p    = (float*)p;            p += (size_t)DEPTH * N1P * 4;

  hipMemcpyAsync(xw, x_in, (size_t)MROWS * DMODEL * 4, hipMemcpyDeviceToDevice, stream);

  conv_bf16_kernel<<<6144, 256, 0, stream>>>(w_in, w_in_b, (size_t)DEPTH * 3 * DMODEL * DMODEL);
  conv_bf16_kernel<<<2048, 256, 0, stream>>>(w_out, w_out_b, (size_t)DEPTH * DMODEL * DMODEL);
  conv_w1_kernel<<<11008, 256, 0, stream>>>(w1, w1p);
  conv_b1_kernel<<<86, 256, 0, stream>>>(b1, b1p);
  conv_w2_kernel<<<5504, 256, 0, stream>>>(w2, w2p);

  for (int i = 0; i < DEPTH; ++i) {
    rmsnorm_kernel<true><<<MROWS, 256, 0, stream>>>(xw, g_attn + i * DMODEL, abuf);
    // qkv: (M,N,K) = (2048, 3072, 1024), bf16 out
    gemm_bt<64, 0, false><<<dim3(48, 16), 256, 0, stream>>>(
        abuf, w_in_b + (size_t)i * 3 * DMODEL * DMODEL, b_in + i * 3 * DMODEL,
        qkvb, MROWS, 3 * DMODEL, DMODEL, 16, 16);
    attn_kernel<<<dim3(16, 32, NSPLIT), 256, 0, stream>>>(qkvb, slopes, Opart, mlb);
    attn_combine<<<2048, 256, 0, stream>>>(Opart, mlb, obuf);
    // out-proj: (2048, 1024, 1024), split-K=2, atomic into xw (residual)
    gemm_bt<64, 3, true><<<dim3(16, 16, 2), 256, 0, stream>>>(
        obuf, w_out_b + (size_t)i * DMODEL * DMODEL, b_out + i * DMODEL,
        xw, MROWS, DMODEL, DMODEL, 8, 16);
    rmsnorm_kernel<true><<<MROWS, 256, 0, stream>>>(xw, g_ff + i * DMODEL, abuf);
    // w1 + GEGLU: (2048, 5504, 1024) -> gbuf (2048 x 2752 bf16)
    gemm_bt<64, 2, false><<<dim3(86, 16), 256, 0, stream>>>(
        abuf, w1p + (size_t)i * N1P * DMODEL, b1p + i * N1P,
        gbuf, MROWS, N1P, DMODEL, 16, 16);
    // w2: (2048, 1024, 2752), split-K=2 (22+21 steps), atomic into xw
    gemm_bt<64, 3, true><<<dim3(16, 16, 2), 256, 0, stream>>>(
        gbuf, w2p + (size_t)i * DMODEL * INNERP, b2 + i * DMODEL,
        xw, MROWS, DMODEL, INNERP, 22, 43);
  }
  rmsnorm_kernel<false><<<MROWS, 256, 0, stream>>>(xw, g_final, d_out);
}